// Round 3
// baseline (2376.473 us; speedup 1.0000x reference)
//
#include <hip/hip_runtime.h>
#include <hip/hip_bf16.h>

// InteractionBlock: per-edge radial MLP (8->64->64->768) + tensor product
// contraction + scatter-sum + self-interaction + batchnorm epilogue.
// Round 2: dual-dtype (runtime-detected bf16 vs f32 inputs/outputs) +
// ws_size sentinel diagnostic. Core pipeline unchanged from round 1.

#define N_NODES_C 50000
#define N_EDGES_C 300000
#define ALPHA_C 0.20412414523193154f   // 1/sqrt(24)
#define INV_SQRT3_C 0.5773502691896258f
#define BN_EPS_C 1e-5f

typedef unsigned int u32;
typedef unsigned short u16;

// workspace layout (float offsets) — total 2,455,040 floats = 9,820,160 B
#define OFF_STATS 0u            // 40: sum_s[16], sum_ss[16], sum_vv[8]
#define OFF_FLAG  48u           // u32: 1 if inputs detected as f32, else 0
#define OFF_W3T   64u           // 49152  (W3T[idx*64+k])
#define OFF_W1T   49216u        // 512    (W1T[j*8+i])
#define OFF_B1    49728u        // 64
#define OFF_W2T   49792u        // 4096   (W2T[j*64+k])
#define OFF_B2    53888u        // 64
#define OFF_B3    53952u        // 768
#define OFF_SI0   54720u        // 256    (si0T[w*16+u], pre-scaled 1/4)
#define OFF_SI1   54976u        // 64     (si1T[w*8+u], pre-scaled 1/sqrt8)
#define OFF_AGG   55040u        // 50000*48 = 2,400,000 (svb reuses in place)
#define REQ_WS_BYTES ((size_t)(55040u + 2400000u) * 4u)

__device__ __forceinline__ float bflo(u32 u){ union{u32 i; float f;} c; c.i = u<<16; return c.f; }
__device__ __forceinline__ float bfhi(u32 u){ union{u32 i; float f;} c; c.i = u & 0xffff0000u; return c.f; }
__device__ __forceinline__ float b2f(__hip_bfloat16 b){ return (float)b; }
__device__ __forceinline__ u16 f2bf(float f){
    union{float f; u32 i;} c; c.f = f;
    u32 r = c.i + 0x7fffu + ((c.i>>16)&1u);
    return (u16)(r>>16);
}
__device__ __forceinline__ float sigmoidf_(float x){ return 1.0f/(1.0f+__expf(-x)); }
__device__ __forceinline__ float siluf_(float x){ return x*sigmoidf_(x); }

// dtype-dispatched scalar read
__device__ __forceinline__ float rdv(const void* p, int idx, bool fm){
    return fm ? ((const float*)p)[idx] : b2f(((const __hip_bfloat16*)p)[idx]);
}

// ---------------- detect: are float inputs f32 or bf16? ----------------
// True bf16 N(0,1) data: both u16 halves of each word decode to bf16 with
// exponent in [90,140] (or exact zero). f32 data: the low u16 is mantissa
// bits -> uniform-random exponent -> ~80% implausible. 64 words sampled.
__global__ void detect_kernel(const u32* __restrict__ nfw, u32* __restrict__ flagp){
    int t = threadIdx.x;            // 64 threads
    u32 w = nfw[t];
    int bad = 0;
    u32 lo = w & 0xffffu, hi = w >> 16;
    u32 elo = (lo >> 7) & 0xffu, ehi = (hi >> 7) & 0xffu;
    if (!(lo == 0u || (elo >= 90u && elo <= 140u))) bad++;
    if (!(hi == 0u || (ehi >= 90u && ehi <= 140u))) bad++;
    for (int off=32; off; off>>=1) bad += __shfl_down(bad, off);
    if (t == 0) flagp[0] = (bad >= 8) ? 1u : 0u;
}

// ---------------- sentinel: ws too small diagnostic ----------------
__global__ __launch_bounds__(256) void fill_kernel(u32* __restrict__ p, int n, u32 v){
    int i = blockIdx.x*256 + threadIdx.x;
    if (i < n) p[i] = v;
}

// ---------------- prep: convert/transpose weights to f32 in ws ----------------
__global__ __launch_bounds__(256) void prep_kernel(
    const void* __restrict__ W1, const void* __restrict__ b1,
    const void* __restrict__ W2, const void* __restrict__ b2,
    const void* __restrict__ W3, const void* __restrict__ b3,
    const void* __restrict__ si0, const void* __restrict__ si1,
    float* __restrict__ ws)
{
    const bool fm = ((const u32*)(ws + OFF_FLAG))[0] != 0u;
    int i = blockIdx.x*256 + threadIdx.x;
    if (i < 49152){ int idx = i>>6, k = i&63; ws[OFF_W3T+i] = rdv(W3, k*768+idx, fm); return; }
    i -= 49152;
    if (i < 512){ int j=i>>3, t=i&7; ws[OFF_W1T+i] = rdv(W1, t*64+j, fm); return; }
    i -= 512;
    if (i < 64){ ws[OFF_B1+i] = rdv(b1, i, fm); return; }
    i -= 64;
    if (i < 4096){ int j=i>>6, k=i&63; ws[OFF_W2T+i] = rdv(W2, k*64+j, fm); return; }
    i -= 4096;
    if (i < 64){ ws[OFF_B2+i] = rdv(b2, i, fm); return; }
    i -= 64;
    if (i < 768){ ws[OFF_B3+i] = rdv(b3, i, fm); return; }
    i -= 768;
    if (i < 256){ int w=i>>4, u=i&15; ws[OFF_SI0+i] = rdv(si0, u*16+w, fm)*0.25f; return; }
    i -= 256;
    if (i < 64){ int w=i>>3, u=i&7; ws[OFF_SI1+i] = rdv(si1, u*8+w, fm)*0.35355339059327373f; return; }
}

// ---------------- edge kernel: MLP + tensor product + scatter ----------------
__global__ __launch_bounds__(256) void edge_kernel(
    const void* __restrict__ nfv,
    const void* __restrict__ eshv,
    const void* __restrict__ ebv,
    const int* __restrict__ eidx,
    const float* __restrict__ ws,
    float* __restrict__ agg)
{
    __shared__ float smem[64*256];   // 64 KiB: h2 staging (slots 0..63), then coeffs (0..47)
    const float* W1T = ws + OFF_W1T;
    const float* b1f = ws + OFF_B1;
    const float* W2T = ws + OFF_W2T;
    const float* b2f = ws + OFF_B2;
    const float* W3T = ws + OFF_W3T;
    const float* b3f = ws + OFF_B3;
    const bool fm = ((const u32*)(ws + OFF_FLAG))[0] != 0u;

    const int tid = threadIdx.x;
    const int e = blockIdx.x*256 + tid;
    if (e >= N_EDGES_C) return;

    const int src = eidx[e];

    float sh0, sh1x, sh1y, sh1z;
    float f[40];
    float bas[8];
    if (!fm){
        const u32* p = (const u32*)((const __hip_bfloat16*)eshv + (size_t)e*4);
        u32 a = p[0], b = p[1];
        sh0 = bflo(a); sh1x = bfhi(a); sh1y = bflo(b); sh1z = bfhi(b);
        const uint4* q = (const uint4*)((const __hip_bfloat16*)nfv + (size_t)src*40);
        #pragma unroll
        for (int i=0;i<5;i++){
            uint4 r = q[i];
            f[i*8+0]=bflo(r.x); f[i*8+1]=bfhi(r.x);
            f[i*8+2]=bflo(r.y); f[i*8+3]=bfhi(r.y);
            f[i*8+4]=bflo(r.z); f[i*8+5]=bfhi(r.z);
            f[i*8+6]=bflo(r.w); f[i*8+7]=bfhi(r.w);
        }
        uint4 r = *(const uint4*)((const __hip_bfloat16*)ebv + (size_t)e*8);
        bas[0]=bflo(r.x); bas[1]=bfhi(r.x); bas[2]=bflo(r.y); bas[3]=bfhi(r.y);
        bas[4]=bflo(r.z); bas[5]=bfhi(r.z); bas[6]=bflo(r.w); bas[7]=bfhi(r.w);
    } else {
        float4 r = *(const float4*)((const float*)eshv + (size_t)e*4);
        sh0 = r.x; sh1x = r.y; sh1y = r.z; sh1z = r.w;
        const float4* q = (const float4*)((const float*)nfv + (size_t)src*40);
        #pragma unroll
        for (int i=0;i<10;i++){
            float4 t = q[i];
            f[i*4+0]=t.x; f[i*4+1]=t.y; f[i*4+2]=t.z; f[i*4+3]=t.w;
        }
        const float4* qb = (const float4*)((const float*)ebv + (size_t)e*8);
        float4 t0 = qb[0], t1 = qb[1];
        bas[0]=t0.x; bas[1]=t0.y; bas[2]=t0.z; bas[3]=t0.w;
        bas[4]=t1.x; bas[5]=t1.y; bas[6]=t1.z; bas[7]=t1.w;
    }

    // h1 = silu(basis @ W1 + b1)
    float h1[64];
    #pragma unroll
    for (int j=0;j<64;j++){
        const float* w = W1T + j*8;
        float t0 = b1f[j] + bas[0]*w[0] + bas[4]*w[4];
        float t1 = bas[1]*w[1] + bas[5]*w[5];
        float t2 = bas[2]*w[2] + bas[6]*w[6];
        float t3 = bas[3]*w[3] + bas[7]*w[7];
        h1[j] = siluf_((t0+t1)+(t2+t3));
    }
    // h2 = silu(h1 @ W2 + b2) -> LDS (rolled j), then reg readback
    #pragma unroll 1
    for (int j=0;j<64;j++){
        const float* w = W2T + j*64;
        float t0=b2f[j], t1=0.f, t2=0.f, t3=0.f;
        #pragma unroll
        for (int k=0;k<64;k+=4){
            t0 += h1[k]*w[k];     t1 += h1[k+1]*w[k+1];
            t2 += h1[k+2]*w[k+2]; t3 += h1[k+3]*w[k+3];
        }
        smem[j*256+tid] = siluf_((t0+t1)+(t2+t3));
    }
    float h2[64];
    #pragma unroll
    for (int k=0;k<64;k++) h2[k] = smem[k*256+tid];

    // stage contraction coeffs in LDS (same-thread column; ordering safe)
    // slots 0..15: sx ; 16..23: dot_vv/sqrt3 ; 24..47: sh0*vx
    #pragma unroll
    for (int u=0;u<16;u++) smem[u*256+tid] = f[u];
    #pragma unroll
    for (int u=0;u<8;u++){
        float x0=f[16+u*3], x1=f[17+u*3], x2=f[18+u*3];
        smem[(16+u)*256+tid] = (x0*sh1x + x1*sh1y + x2*sh1z)*INV_SQRT3_C;
        smem[(24+u*3+0)*256+tid] = x0*sh0;
        smem[(24+u*3+1)*256+tid] = x1*sh0;
        smem[(24+u*3+2)*256+tid] = x2*sh0;
    }

    auto dot64 = [&](const float* c, float init)->float{
        float t0=init, t1=0.f, t2=0.f, t3=0.f;
        #pragma unroll
        for (int k=0;k<64;k+=4){
            t0 += h2[k]*c[k];     t1 += h2[k+1]*c[k+1];
            t2 += h2[k+2]*c[k+2]; t3 += h2[k+3]*c[k+3];
        }
        return (t0+t1)+(t2+t3);
    };

    float outs[24];
    #pragma unroll
    for (int w=0;w<24;w++) outs[w]=0.f;
    // ss block: tp_w[u*24+w], coeff sx[u] (sh0 applied after)
    #pragma unroll 1
    for (int u=0;u<16;u++){
        float au = smem[u*256+tid];
        const float* cb = W3T + (size_t)(u*24)*64;
        const float* bb = b3f + u*24;
        #pragma unroll
        for (int w=0;w<24;w++) outs[w] += au * dot64(cb + w*64, bb[w]);
    }
    #pragma unroll
    for (int w=0;w<24;w++) outs[w] *= sh0;
    // vv block: tp_w[384+u*24+w], coeff dot_vv[u]
    #pragma unroll 1
    for (int u=0;u<8;u++){
        float au = smem[(16+u)*256+tid];
        const float* cb = W3T + (size_t)(384+u*24)*64;
        const float* bb = b3f + 384+u*24;
        #pragma unroll
        for (int w=0;w<24;w++) outs[w] += au * dot64(cb + w*64, bb[w]);
    }
    // sv block: tp_w[576+u*8+w], coeff sx[u] (sh1[i] applied at end)
    float tsv[8];
    #pragma unroll
    for (int w=0;w<8;w++) tsv[w]=0.f;
    #pragma unroll 1
    for (int u=0;u<16;u++){
        float au = smem[u*256+tid];
        const float* cb = W3T + (size_t)(576+u*8)*64;
        const float* bb = b3f + 576+u*8;
        #pragma unroll
        for (int w=0;w<8;w++) tsv[w] += au * dot64(cb + w*64, bb[w]);
    }
    // vs block: tp_w[704+u*8+w], coeff sh0*vx[u][i]
    float av0[8], av1[8], av2[8];
    #pragma unroll
    for (int w=0;w<8;w++){ av0[w]=0.f; av1[w]=0.f; av2[w]=0.f; }
    #pragma unroll 1
    for (int u=0;u<8;u++){
        float x0 = smem[(24+u*3+0)*256+tid];
        float x1 = smem[(24+u*3+1)*256+tid];
        float x2 = smem[(24+u*3+2)*256+tid];
        const float* cb = W3T + (size_t)(704+u*8)*64;
        const float* bb = b3f + 704+u*8;
        #pragma unroll
        for (int w=0;w<8;w++){
            float tp = dot64(cb + w*64, bb[w]);
            av0[w]+=x0*tp; av1[w]+=x1*tp; av2[w]+=x2*tp;
        }
    }

    const int dst = eidx[N_EDGES_C + e];
    float* dp = agg + (size_t)dst*48;
    #pragma unroll
    for (int w=0;w<24;w++) atomicAdd(dp+w, outs[w]*ALPHA_C);
    #pragma unroll
    for (int w=0;w<8;w++){
        atomicAdd(dp+24+w*3+0, (tsv[w]*sh1x + av0[w])*ALPHA_C);
        atomicAdd(dp+24+w*3+1, (tsv[w]*sh1y + av1[w])*ALPHA_C);
        atomicAdd(dp+24+w*3+2, (tsv[w]*sh1z + av2[w])*ALPHA_C);
    }
}

// ---------------- node kernel: gate + self-interaction + BN stats ----------------
// svb is written IN PLACE over agg (row stride 48, first 40 slots).
__global__ __launch_bounds__(256) void node_kernel(
    const float* __restrict__ ws,
    float* __restrict__ agg,
    float* __restrict__ stats)
{
    const float* si0T = ws + OFF_SI0;
    const float* si1T = ws + OFF_SI1;
    const int n = blockIdx.x*256 + threadIdx.x;
    const bool act = n < N_NODES_C;

    float a[48];
    if (act){
        const float4* p = (const float4*)(agg + (size_t)n*48);
        #pragma unroll
        for (int q=0;q<12;q++){ float4 r=p[q]; a[q*4]=r.x; a[q*4+1]=r.y; a[q*4+2]=r.z; a[q*4+3]=r.w; }
    } else {
        #pragma unroll
        for (int j=0;j<48;j++) a[j]=0.f;
    }
    float spre[16];
    #pragma unroll
    for (int u=0;u<16;u++) spre[u]=siluf_(a[u]);
    float v[24];
    #pragma unroll
    for (int u=0;u<8;u++){
        float g = sigmoidf_(a[16+u]);
        v[u*3+0]=a[24+u*3+0]*g; v[u*3+1]=a[24+u*3+1]*g; v[u*3+2]=a[24+u*3+2]*g;
    }
    float so[16];
    #pragma unroll
    for (int w=0;w<16;w++){
        const float* c = si0T + w*16;
        float t0=0.f,t1=0.f,t2=0.f,t3=0.f;
        #pragma unroll
        for (int u=0;u<16;u+=4){ t0+=spre[u]*c[u]; t1+=spre[u+1]*c[u+1]; t2+=spre[u+2]*c[u+2]; t3+=spre[u+3]*c[u+3]; }
        so[w]=(t0+t1)+(t2+t3);
    }
    float vo[24];
    #pragma unroll
    for (int w=0;w<8;w++){
        const float* c = si1T + w*8;
        float a0=0.f,a1=0.f,a2=0.f;
        #pragma unroll
        for (int u=0;u<8;u++){ a0+=v[u*3]*c[u]; a1+=v[u*3+1]*c[u]; a2+=v[u*3+2]*c[u]; }
        vo[w*3]=a0; vo[w*3+1]=a1; vo[w*3+2]=a2;
    }
    if (act){
        float4* op = (float4*)(agg + (size_t)n*48);   // in-place svb
        op[0]=make_float4(so[0],so[1],so[2],so[3]);
        op[1]=make_float4(so[4],so[5],so[6],so[7]);
        op[2]=make_float4(so[8],so[9],so[10],so[11]);
        op[3]=make_float4(so[12],so[13],so[14],so[15]);
        #pragma unroll
        for (int q=0;q<6;q++) op[4+q]=make_float4(vo[q*4],vo[q*4+1],vo[q*4+2],vo[q*4+3]);
    }
    // BN statistics (inactive threads contribute exact zeros)
    float r[40];
    #pragma unroll
    for (int w=0;w<16;w++){ r[w]=so[w]; r[16+w]=so[w]*so[w]; }
    #pragma unroll
    for (int w=0;w<8;w++) r[32+w]=(vo[w*3]*vo[w*3]+vo[w*3+1]*vo[w*3+1]+vo[w*3+2]*vo[w*3+2])*(1.0f/3.0f);
    #pragma unroll
    for (int j=0;j<40;j++){
        float x = r[j];
        for (int off=32; off; off>>=1) x += __shfl_down(x, off);
        r[j]=x;
    }
    if ((threadIdx.x & 63)==0){
        #pragma unroll
        for (int j=0;j<40;j++) atomicAdd(stats+j, r[j]);
    }
}

// ---------------- finalize: batchnorm + residual + dtype-dispatched store ----------------
__global__ __launch_bounds__(256) void final_kernel(
    const float* __restrict__ ws, const float* __restrict__ svb,
    const void* __restrict__ nfv,
    const void* __restrict__ bnws, const void* __restrict__ bnbs,
    const void* __restrict__ bnwv,
    void* __restrict__ outv)
{
    const float* stats = ws + OFF_STATS;
    const bool fm = ((const u32*)(ws + OFF_FLAG))[0] != 0u;
    const int n = blockIdx.x*256 + threadIdx.x;
    if (n >= N_NODES_C) return;
    const float invN = 1.0f/(float)N_NODES_C;
    const float* s = svb + (size_t)n*48;   // stride 48 (in-place over agg)
    float nfr[40];
    if (!fm){
        const uint4* q = (const uint4*)((const __hip_bfloat16*)nfv + (size_t)n*40);
        #pragma unroll
        for (int i=0;i<5;i++){
            uint4 r = q[i];
            nfr[i*8+0]=bflo(r.x); nfr[i*8+1]=bfhi(r.x);
            nfr[i*8+2]=bflo(r.y); nfr[i*8+3]=bfhi(r.y);
            nfr[i*8+4]=bflo(r.z); nfr[i*8+5]=bfhi(r.z);
            nfr[i*8+6]=bflo(r.w); nfr[i*8+7]=bfhi(r.w);
        }
    } else {
        const float4* q = (const float4*)((const float*)nfv + (size_t)n*40);
        #pragma unroll
        for (int i=0;i<10;i++){
            float4 t = q[i];
            nfr[i*4+0]=t.x; nfr[i*4+1]=t.y; nfr[i*4+2]=t.z; nfr[i*4+3]=t.w;
        }
    }
    float vals[40];
    #pragma unroll
    for (int w=0;w<16;w++){
        float mean = stats[w]*invN;
        float var  = fmaxf(stats[16+w]*invN - mean*mean, 0.0f);
        float is   = rsqrtf(var + BN_EPS_C) * rdv(bnws, w, fm);
        vals[w] = (s[w]-mean)*is + rdv(bnbs, w, fm) + nfr[w];
    }
    #pragma unroll
    for (int w=0;w<8;w++){
        float iv = rsqrtf(fmaxf(stats[32+w]*invN, 0.0f) + BN_EPS_C) * rdv(bnwv, w, fm);
        vals[16+w*3+0] = s[16+w*3+0]*iv + nfr[16+w*3+0];
        vals[16+w*3+1] = s[16+w*3+1]*iv + nfr[16+w*3+1];
        vals[16+w*3+2] = s[16+w*3+2]*iv + nfr[16+w*3+2];
    }
    if (!fm){
        u32 packed[20];
        #pragma unroll
        for (int q=0;q<20;q++) packed[q] = (u32)f2bf(vals[2*q]) | ((u32)f2bf(vals[2*q+1])<<16);
        uint4* op = (uint4*)((u16*)outv + (size_t)n*40);
        #pragma unroll
        for (int q=0;q<5;q++) op[q] = make_uint4(packed[q*4],packed[q*4+1],packed[q*4+2],packed[q*4+3]);
    } else {
        float4* op = (float4*)((float*)outv + (size_t)n*40);
        #pragma unroll
        for (int q=0;q<10;q++) op[q] = make_float4(vals[q*4],vals[q*4+1],vals[q*4+2],vals[q*4+3]);
    }
}

extern "C" void kernel_launch(void* const* d_in, const int* in_sizes, int n_in,
                              void* d_out, int out_size, void* d_ws, size_t ws_size,
                              hipStream_t stream)
{
    const void* nf     = d_in[0];
    const void* esh    = d_in[1];
    const void* ebasis = d_in[2];
    const int*  eidx   = (const int*)d_in[3];
    const void* W1 = d_in[4];
    const void* b1 = d_in[5];
    const void* W2 = d_in[6];
    const void* b2 = d_in[7];
    const void* W3 = d_in[8];
    const void* b3 = d_in[9];
    const void* si0 = d_in[10];
    const void* si1 = d_in[11];
    const void* bnws = d_in[12];
    const void* bnbs = d_in[13];
    const void* bnwv = d_in[14];

    float* ws    = (float*)d_ws;
    float* stats = ws + OFF_STATS;
    float* agg   = ws + OFF_AGG;

    if (ws_size < REQ_WS_BYTES){
        // diagnostic sentinel: ~1000.0 whether read as bf16 or f32
        int nw = out_size/2;   // covers out_size u16s (bf16 case fully)
        fill_kernel<<<(nw+255)/256, 256, 0, stream>>>((u32*)d_out, nw, 0x447A447Au);
        return;
    }

    hipMemsetAsync(stats, 0, 48*sizeof(float), stream);
    hipMemsetAsync(agg, 0, (size_t)2400000*sizeof(float), stream);
    detect_kernel<<<1, 64, 0, stream>>>((const u32*)nf, (u32*)(ws + OFF_FLAG));
    prep_kernel<<<215, 256, 0, stream>>>(W1,b1,W2,b2,W3,b3,si0,si1, ws);
    edge_kernel<<<(N_EDGES_C+255)/256, 256, 0, stream>>>(nf, esh, ebasis, eidx, ws, agg);
    node_kernel<<<(N_NODES_C+255)/256, 256, 0, stream>>>(ws, agg, stats);
    final_kernel<<<(N_NODES_C+255)/256, 256, 0, stream>>>(ws, agg, nf, bnws, bnbs, bnwv, d_out);
}

// Round 8
// 1274.547 us; speedup vs baseline: 1.8646x; 1.8646x over previous
//
#include <hip/hip_runtime.h>
#include <hip/hip_bf16.h>

// InteractionBlock: per-edge radial MLP (8->64->64->768) + tensor product
// contraction + scatter-sum + self-interaction + batchnorm epilogue.
// Round 8: MFMA tp GEMM (probe-verified, all 4 D-regs) + fully PER-THREAD
// contraction (round-3 structure: own registers, no shfl routing, no quad
// reduction). tp stored transposed tpb[col][edge] (lane-stride-1 reads).
// VALU-tp fallback (mode 2) keeps correctness if probe fails.

#define N_NODES_C 50000
#define N_EDGES_C 300000
#define ALPHA_C 0.20412414523193154f   // 1/sqrt(24)
#define INV_SQRT3_C 0.5773502691896258f
#define BN_EPS_C 1e-5f

typedef unsigned int u32;
typedef unsigned long long u64;
typedef unsigned short u16;
typedef __attribute__((ext_vector_type(8))) short bf16x8;
typedef __attribute__((ext_vector_type(4))) float f32x4;

// workspace layout (float offsets) — total 2,504,192 floats = 10,016,768 B
#define OFF_STATS 0u            // 40
#define OFF_FLAG  48u           // u32 dtype flag
#define OFF_W3T   64u           // 49152 floats: frag-packed W3 bf16 hi + lo
#define OFF_W1T   49216u        // 512
#define OFF_B1    49728u        // 64
#define OFF_W2T   49792u        // 4096
#define OFF_B2    53888u        // 64
#define OFF_B3    53952u        // 768
#define OFF_SI0   54720u        // 256
#define OFF_SI1   54976u        // 64
#define OFF_WCM   55040u        // 49152: W3 col-major f32 Wcm[col*64+k]
#define OFF_AGG   104192u       // 50000*48 = 2,400,000 (svb reuses in place)
#define REQ_WS_BYTES ((size_t)(104192u + 2400000u) * 4u)

__device__ __forceinline__ float bflo(u32 u){ union{u32 i; float f;} c; c.i = u<<16; return c.f; }
__device__ __forceinline__ float bfhi(u32 u){ union{u32 i; float f;} c; c.i = u & 0xffff0000u; return c.f; }
__device__ __forceinline__ float b2f(__hip_bfloat16 b){ return (float)b; }
__device__ __forceinline__ u16 f2bf(float f){
    union{float f; u32 i;} c; c.f = f;
    u32 r = c.i + 0x7fffu + ((c.i>>16)&1u);
    return (u16)(r>>16);
}
__device__ __forceinline__ float bfu(u16 x){ return bflo((u32)x); }
__device__ __forceinline__ float sigmoidf_(float x){ return 1.0f/(1.0f+__expf(-x)); }
__device__ __forceinline__ float siluf_(float x){ return x*sigmoidf_(x); }
__device__ __forceinline__ float rdv(const void* p, int idx, bool fm){
    return fm ? ((const float*)p)[idx] : b2f(((const __hip_bfloat16*)p)[idx]);
}
__device__ __forceinline__ float sel4(float a, float b, float c, float d, int q){
    float lo = (q&1) ? b : a;
    float hi = (q&1) ? d : c;
    return (q&2) ? hi : lo;
}
__device__ __forceinline__ float sel8(float a0,float a1,float a2,float a3,
                                      float a4,float a5,float a6,float a7,int q){
    float x0=(q&1)?a1:a0, x1=(q&1)?a3:a2, x2=(q&1)?a5:a4, x3=(q&1)?a7:a6;
    float y0=(q&2)?x1:x0, y1=(q&2)?x3:x2;
    return (q&4)?y1:y0;
}

// ---------------- detect dtype ----------------
__global__ void detect_kernel(const u32* __restrict__ nfw, u32* __restrict__ flagp){
    int t = threadIdx.x;
    u32 w = nfw[t];
    int bad = 0;
    u32 lo = w & 0xffffu, hi = w >> 16;
    u32 elo = (lo >> 7) & 0xffu, ehi = (hi >> 7) & 0xffu;
    if (!(lo == 0u || (elo >= 90u && elo <= 140u))) bad++;
    if (!(hi == 0u || (ehi >= 90u && ehi <= 140u))) bad++;
    for (int off=32; off; off>>=1) bad += __shfl_down(bad, off);
    if (t == 0) flagp[0] = (bad >= 8) ? 1u : 0u;
}

__global__ __launch_bounds__(256) void fill_kernel(u32* __restrict__ p, int n, u32 v){
    int i = blockIdx.x*256 + threadIdx.x;
    if (i < n) p[i] = v;
}

// ---------------- prep ----------------
__global__ __launch_bounds__(256) void prep_kernel(
    const void* __restrict__ W1, const void* __restrict__ b1,
    const void* __restrict__ W2, const void* __restrict__ b2,
    const void* __restrict__ W3, const void* __restrict__ b3,
    const void* __restrict__ si0, const void* __restrict__ si1,
    float* __restrict__ ws)
{
    const bool fm = ((const u32*)(ws + OFF_FLAG))[0] != 0u;
    int i = blockIdx.x*256 + threadIdx.x;
    if (i < 49152){
        int j = i & 7, lane = (i>>3)&63, kh = (i>>9)&1, nt = i>>10;
        int n = lane & 15, qd = lane >> 4;
        int k = kh*32 + qd*8 + j;
        int col = nt*16 + n;
        float v = rdv(W3, k*768 + col, fm);
        u16 hv = f2bf(v);
        float hf = bflo((u32)hv);
        u16 lv = f2bf(v - hf);
        u16* BH = (u16*)(ws + OFF_W3T);
        BH[i] = hv;
        BH[49152 + i] = lv;
        return;
    }
    i -= 49152;
    if (i < 512){ int j=i>>3, t=i&7; ws[OFF_W1T+i] = rdv(W1, t*64+j, fm); return; }
    i -= 512;
    if (i < 64){ ws[OFF_B1+i] = rdv(b1, i, fm); return; }
    i -= 64;
    if (i < 4096){ int j=i>>6, k=i&63; ws[OFF_W2T+i] = rdv(W2, k*64+j, fm); return; }
    i -= 4096;
    if (i < 64){ ws[OFF_B2+i] = rdv(b2, i, fm); return; }
    i -= 64;
    if (i < 768){ ws[OFF_B3+i] = rdv(b3, i, fm); return; }
    i -= 768;
    if (i < 256){ int w=i>>4, u=i&15; ws[OFF_SI0+i] = rdv(si0, u*16+w, fm)*0.25f; return; }
    i -= 256;
    if (i < 64){ int w=i>>3, u=i&7; ws[OFF_SI1+i] = rdv(si1, u*8+w, fm)*0.35355339059327373f; return; }
    i -= 64;
    if (i < 49152){ int col=i>>6, k=i&63; ws[OFF_WCM+i] = rdv(W3, k*768+col, fm); return; }
}

// ---------------- edge kernel ----------------
__global__ __launch_bounds__(128) void edge_kernel(
    const void* __restrict__ nfv,
    const void* __restrict__ eshv,
    const void* __restrict__ ebv,
    const int* __restrict__ eidx,
    const float* __restrict__ ws,
    float* __restrict__ agg)
{
    __shared__ __align__(16) float sB3[768];          //  3072 B
    __shared__ __align__(16) u16   h2hi[2][64][72];   // 18432 B
    __shared__ __align__(16) float tpb[2][48][67];    // 25728 B  (total 47232)

    const bool fm = ((const u32*)(ws + OFF_FLAG))[0] != 0u;
    const int tid  = threadIdx.x;
    const int wv   = tid >> 6;
    const int lane = tid & 63;
    const int m    = lane & 15;
    const int quad = lane >> 4;
    const int e0   = blockIdx.x*128;
    const int e    = e0 + tid;
    const bool act = e < N_EDGES_C;

    for (int idx = tid; idx < 768; idx += 128) sB3[idx] = ws[OFF_B3 + idx];
    __syncthreads();

    // ---- inputs (dtype-dispatched; round-3-verified) ----
    float sh0=0.f, sh1x=0.f, sh1y=0.f, sh1z=0.f;
    float f[40];
    float bas[8];
    #pragma unroll
    for (int i=0;i<40;i++) f[i]=0.f;
    #pragma unroll
    for (int i=0;i<8;i++) bas[i]=0.f;
    if (act){
        const int src = eidx[e];
        if (!fm){
            const u32* p = (const u32*)((const __hip_bfloat16*)eshv + (size_t)e*4);
            u32 a = p[0], b = p[1];
            sh0 = bflo(a); sh1x = bfhi(a); sh1y = bflo(b); sh1z = bfhi(b);
            const uint4* qq = (const uint4*)((const __hip_bfloat16*)nfv + (size_t)src*40);
            #pragma unroll
            for (int i=0;i<5;i++){
                uint4 r = qq[i];
                f[i*8+0]=bflo(r.x); f[i*8+1]=bfhi(r.x);
                f[i*8+2]=bflo(r.y); f[i*8+3]=bfhi(r.y);
                f[i*8+4]=bflo(r.z); f[i*8+5]=bfhi(r.z);
                f[i*8+6]=bflo(r.w); f[i*8+7]=bfhi(r.w);
            }
            uint4 r = *(const uint4*)((const __hip_bfloat16*)ebv + (size_t)e*8);
            bas[0]=bflo(r.x); bas[1]=bfhi(r.x); bas[2]=bflo(r.y); bas[3]=bfhi(r.y);
            bas[4]=bflo(r.z); bas[5]=bfhi(r.z); bas[6]=bflo(r.w); bas[7]=bfhi(r.w);
        } else {
            float4 r = *(const float4*)((const float*)eshv + (size_t)e*4);
            sh0 = r.x; sh1x = r.y; sh1y = r.z; sh1z = r.w;
            const float4* qq = (const float4*)((const float*)nfv + (size_t)src*40);
            #pragma unroll
            for (int i=0;i<10;i++){
                float4 t = qq[i];
                f[i*4+0]=t.x; f[i*4+1]=t.y; f[i*4+2]=t.z; f[i*4+3]=t.w;
            }
            const float4* qb = (const float4*)((const float*)ebv + (size_t)e*8);
            float4 t0 = qb[0], t1 = qb[1];
            bas[0]=t0.x; bas[1]=t0.y; bas[2]=t0.z; bas[3]=t0.w;
            bas[4]=t1.x; bas[5]=t1.y; bas[6]=t1.z; bas[7]=t1.w;
        }
    }

    // ---- MLP1 ----
    const float* W1T = ws + OFF_W1T;
    const float* b1f = ws + OFF_B1;
    float h1[64];
    #pragma unroll
    for (int j=0;j<64;j++){
        const float* w = W1T + j*8;
        float t0 = b1f[j] + bas[0]*w[0] + bas[4]*w[4];
        float t1 = bas[1]*w[1] + bas[5]*w[5];
        float t2 = bas[2]*w[2] + bas[6]*w[6];
        float t3 = bas[3]*w[3] + bas[7]*w[7];
        h1[j] = siluf_((t0+t1)+(t2+t3));
    }

    // ---- MLP2 -> bf16 h2 rows in LDS ----
    const float* W2T = ws + OFF_W2T;
    const float* b2f = ws + OFF_B2;
    #pragma unroll 1
    for (int j=0;j<64;j++){
        const float* w = W2T + j*64;
        float t0=b2f[j], t1=0.f, t2=0.f, t3=0.f;
        #pragma unroll
        for (int k=0;k<64;k+=4){
            t0 += h1[k]*w[k];     t1 += h1[k+1]*w[k+1];
            t2 += h1[k+2]*w[k+2]; t3 += h1[k+3]*w[k+3];
        }
        h2hi[wv][lane][j] = f2bf(siluf_((t0+t1)+(t2+t3)));
    }
    __syncthreads();

    // ---- A fragments (all 4 g-tiles, both k-halves) ----
    bf16x8 Afr[4][2];
    #pragma unroll
    for (int g=0;g<4;g++){
        Afr[g][0] = *(const bf16x8*)&h2hi[wv][g*16+m][quad*8];
        Afr[g][1] = *(const bf16x8*)&h2hi[wv][g*16+m][32 + quad*8];
    }

    const short* BH = (const short*)(ws + OFF_W3T);
    const short* BL = BH + 49152;
    const float* Wcm = ws + OFF_WCM;

    // ---- probe: verify full D mapping (all 4 regs) for g=0, nt=0 ----
    int mode;
    {
        f32x4 accp = {0.f,0.f,0.f,0.f};
        {
            bf16x8 bh = *(const bf16x8*)(BH + (0*64 + lane)*8);
            bf16x8 bl = *(const bf16x8*)(BL + (0*64 + lane)*8);
            accp = __builtin_amdgcn_mfma_f32_16x16x32_bf16(Afr[0][0], bh, accp, 0,0,0);
            accp = __builtin_amdgcn_mfma_f32_16x16x32_bf16(Afr[0][0], bl, accp, 0,0,0);
        }
        {
            bf16x8 bh = *(const bf16x8*)(BH + (1*64 + lane)*8);
            bf16x8 bl = *(const bf16x8*)(BL + (1*64 + lane)*8);
            accp = __builtin_amdgcn_mfma_f32_16x16x32_bf16(Afr[0][1], bh, accp, 0,0,0);
            accp = __builtin_amdgcn_mfma_f32_16x16x32_bf16(Afr[0][1], bl, accp, 0,0,0);
        }
        float ref[4] = {0.f,0.f,0.f,0.f};
        #pragma unroll 1
        for (int k=0;k<64;k++){
            float wval = Wcm[m*64+k];
            #pragma unroll
            for (int r=0;r<4;r++) ref[r] += bfu(h2hi[wv][quad*4+r][k]) * wval;
        }
        bool ok = true;
        #pragma unroll
        for (int r=0;r<4;r++) ok = ok && (fabsf(accp[r]-ref[r]) <= 0.02f*fabsf(ref[r])+0.05f);
        mode = (__ballot(ok) == ~0ull) ? 0 : 2;
    }

    // ---- per-thread contraction coefficients (own registers) ----
    float cssx[16], vxsh0[24], dvv[8];
    #pragma unroll
    for (int u=0;u<16;u++) cssx[u] = f[u]*sh0;
    #pragma unroll
    for (int j=0;j<24;j++) vxsh0[j] = f[16+j]*sh0;
    #pragma unroll
    for (int u=0;u<8;u++)
        dvv[u] = (f[16+u*3]*sh1x + f[17+u*3]*sh1y + f[18+u*3]*sh1z)*INV_SQRT3_C;

    float outs[24], tsv[8], av0[8], av1[8], av2[8];
    #pragma unroll
    for (int t=0;t<24;t++) outs[t]=0.f;
    #pragma unroll
    for (int t=0;t<8;t++){ tsv[t]=0.f; av0[t]=0.f; av1[t]=0.f; av2[t]=0.f; }

    #pragma unroll 1
    for (int cc=0; cc<16; cc++){
        // ---- phase 1: fill tpb[col 0..47][edge 0..63] for cols cc*48.. ----
        if (mode == 0){
            #pragma unroll
            for (int ntl=0; ntl<3; ntl++){
                const int nt = cc*3 + ntl;
                bf16x8 bh0 = *(const bf16x8*)(BH + ((nt*2+0)*64 + lane)*8);
                bf16x8 bl0 = *(const bf16x8*)(BL + ((nt*2+0)*64 + lane)*8);
                bf16x8 bh1 = *(const bf16x8*)(BH + ((nt*2+1)*64 + lane)*8);
                bf16x8 bl1 = *(const bf16x8*)(BL + ((nt*2+1)*64 + lane)*8);
                #pragma unroll
                for (int g=0; g<4; g++){
                    f32x4 acc = {0.f,0.f,0.f,0.f};
                    acc = __builtin_amdgcn_mfma_f32_16x16x32_bf16(Afr[g][0], bh0, acc, 0,0,0);
                    acc = __builtin_amdgcn_mfma_f32_16x16x32_bf16(Afr[g][0], bl0, acc, 0,0,0);
                    acc = __builtin_amdgcn_mfma_f32_16x16x32_bf16(Afr[g][1], bh1, acc, 0,0,0);
                    acc = __builtin_amdgcn_mfma_f32_16x16x32_bf16(Afr[g][1], bl1, acc, 0,0,0);
                    // D: col = nt*16 + (lane&15), row(edge in g-tile) = quad*4+reg
                    #pragma unroll
                    for (int r=0;r<4;r++) tpb[wv][ntl*16+m][g*16+quad*4+r] = acc[r];
                }
            }
        } else {
            // VALU fallback: thread computes its own edge's 48 columns
            #pragma unroll 1
            for (int c=0;c<48;c++){
                float a = 0.f;
                #pragma unroll
                for (int k=0;k<64;k++) a += bfu(h2hi[wv][lane][k]) * Wcm[(size_t)(cc*48+c)*64+k];
                tpb[wv][c][lane] = a;
            }
        }
        __syncthreads();

        // ---- phase 2: per-thread accumulate (lane = edge) ----
        float vals[48];
        #pragma unroll
        for (int c=0;c<48;c++) vals[c] = tpb[wv][c][lane] + sB3[cc*48+c];

        if (cc < 8){              // ss: u = cc*2 + (c>=24), coeff sx[u]*sh0
            float cA = sel8(cssx[0],cssx[2],cssx[4],cssx[6],cssx[8],cssx[10],cssx[12],cssx[14], cc);
            float cB = sel8(cssx[1],cssx[3],cssx[5],cssx[7],cssx[9],cssx[11],cssx[13],cssx[15], cc);
            #pragma unroll
            for (int c=0;c<24;c++) outs[c] += cA*vals[c];
            #pragma unroll
            for (int c=0;c<24;c++) outs[c] += cB*vals[24+c];
        } else if (cc < 12){      // vv: u = (cc-8)*2 + (c>=24), coeff dvv[u]
            int q = cc-8;
            float cA = sel4(dvv[0],dvv[2],dvv[4],dvv[6], q);
            float cB = sel4(dvv[1],dvv[3],dvv[5],dvv[7], q);
            #pragma unroll
            for (int c=0;c<24;c++) outs[c] += cA*vals[c];
            #pragma unroll
            for (int c=0;c<24;c++) outs[c] += cB*vals[24+c];
        } else if (cc == 12){     // sv u=0..5
            #pragma unroll
            for (int c=0;c<48;c++) tsv[c&7] += f[c>>3]*vals[c];
        } else if (cc == 13){     // sv u=6..11
            #pragma unroll
            for (int c=0;c<48;c++) tsv[c&7] += f[6+(c>>3)]*vals[c];
        } else if (cc == 14){     // sv u=12..15 then vs u=0..1
            #pragma unroll
            for (int c=0;c<32;c++) tsv[c&7] += f[12+(c>>3)]*vals[c];
            #pragma unroll
            for (int c=32;c<48;c++){
                const int u=(c-32)>>3, w=(c-32)&7;
                av0[w] += vxsh0[u*3+0]*vals[c];
                av1[w] += vxsh0[u*3+1]*vals[c];
                av2[w] += vxsh0[u*3+2]*vals[c];
            }
        } else {                  // vs u=2..7
            #pragma unroll
            for (int c=0;c<48;c++){
                const int u=2+(c>>3), w=c&7;
                av0[w] += vxsh0[u*3+0]*vals[c];
                av1[w] += vxsh0[u*3+1]*vals[c];
                av2[w] += vxsh0[u*3+2]*vals[c];
            }
        }
        __syncthreads();
    }

    // ---- per-thread atomics (own edge) ----
    if (act){
        const int dst = eidx[N_EDGES_C + e];
        float* dp = agg + (size_t)dst*48;
        #pragma unroll
        for (int w=0;w<24;w++) atomicAdd(dp+w, outs[w]*ALPHA_C);
        #pragma unroll
        for (int w=0;w<8;w++){
            atomicAdd(dp+24+w*3+0, (tsv[w]*sh1x + av0[w])*ALPHA_C);
            atomicAdd(dp+24+w*3+1, (tsv[w]*sh1y + av1[w])*ALPHA_C);
            atomicAdd(dp+24+w*3+2, (tsv[w]*sh1z + av2[w])*ALPHA_C);
        }
    }
}

// ---------------- node kernel ----------------
__global__ __launch_bounds__(256) void node_kernel(
    const float* __restrict__ ws,
    float* __restrict__ agg,
    float* __restrict__ stats)
{
    const float* si0T = ws + OFF_SI0;
    const float* si1T = ws + OFF_SI1;
    const int n = blockIdx.x*256 + threadIdx.x;
    const bool act = n < N_NODES_C;

    float a[48];
    if (act){
        const float4* p = (const float4*)(agg + (size_t)n*48);
        #pragma unroll
        for (int q=0;q<12;q++){ float4 r=p[q]; a[q*4]=r.x; a[q*4+1]=r.y; a[q*4+2]=r.z; a[q*4+3]=r.w; }
    } else {
        #pragma unroll
        for (int j=0;j<48;j++) a[j]=0.f;
    }
    float spre[16];
    #pragma unroll
    for (int u=0;u<16;u++) spre[u]=siluf_(a[u]);
    float v[24];
    #pragma unroll
    for (int u=0;u<8;u++){
        float g = sigmoidf_(a[16+u]);
        v[u*3+0]=a[24+u*3+0]*g; v[u*3+1]=a[24+u*3+1]*g; v[u*3+2]=a[24+u*3+2]*g;
    }
    float so[16];
    #pragma unroll
    for (int w=0;w<16;w++){
        const float* c = si0T + w*16;
        float t0=0.f,t1=0.f,t2=0.f,t3=0.f;
        #pragma unroll
        for (int u=0;u<16;u+=4){ t0+=spre[u]*c[u]; t1+=spre[u+1]*c[u+1]; t2+=spre[u+2]*c[u+2]; t3+=spre[u+3]*c[u+3]; }
        so[w]=(t0+t1)+(t2+t3);
    }
    float vo[24];
    #pragma unroll
    for (int w=0;w<8;w++){
        const float* c = si1T + w*8;
        float a0=0.f,a1=0.f,a2=0.f;
        #pragma unroll
        for (int u=0;u<8;u++){ a0+=v[u*3]*c[u]; a1+=v[u*3+1]*c[u]; a2+=v[u*3+2]*c[u]; }
        vo[w*3]=a0; vo[w*3+1]=a1; vo[w*3+2]=a2;
    }
    if (act){
        float4* op = (float4*)(agg + (size_t)n*48);
        op[0]=make_float4(so[0],so[1],so[2],so[3]);
        op[1]=make_float4(so[4],so[5],so[6],so[7]);
        op[2]=make_float4(so[8],so[9],so[10],so[11]);
        op[3]=make_float4(so[12],so[13],so[14],so[15]);
        #pragma unroll
        for (int q=0;q<6;q++) op[4+q]=make_float4(vo[q*4],vo[q*4+1],vo[q*4+2],vo[q*4+3]);
    }
    float r[40];
    #pragma unroll
    for (int w=0;w<16;w++){ r[w]=so[w]; r[16+w]=so[w]*so[w]; }
    #pragma unroll
    for (int w=0;w<8;w++) r[32+w]=(vo[w*3]*vo[w*3]+vo[w*3+1]*vo[w*3+1]+vo[w*3+2]*vo[w*3+2])*(1.0f/3.0f);
    #pragma unroll
    for (int j=0;j<40;j++){
        float x = r[j];
        for (int off=32; off; off>>=1) x += __shfl_down(x, off);
        r[j]=x;
    }
    if ((threadIdx.x & 63)==0){
        #pragma unroll
        for (int j=0;j<40;j++) atomicAdd(stats+j, r[j]);
    }
}

// ---------------- finalize ----------------
__global__ __launch_bounds__(256) void final_kernel(
    const float* __restrict__ ws, const float* __restrict__ svb,
    const void* __restrict__ nfv,
    const void* __restrict__ bnws, const void* __restrict__ bnbs,
    const void* __restrict__ bnwv,
    void* __restrict__ outv)
{
    const float* stats = ws + OFF_STATS;
    const bool fm = ((const u32*)(ws + OFF_FLAG))[0] != 0u;
    const int n = blockIdx.x*256 + threadIdx.x;
    if (n >= N_NODES_C) return;
    const float invN = 1.0f/(float)N_NODES_C;
    const float* s = svb + (size_t)n*48;
    float nfr[40];
    if (!fm){
        const uint4* q = (const uint4*)((const __hip_bfloat16*)nfv + (size_t)n*40);
        #pragma unroll
        for (int i=0;i<5;i++){
            uint4 r = q[i];
            nfr[i*8+0]=bflo(r.x); nfr[i*8+1]=bfhi(r.x);
            nfr[i*8+2]=bflo(r.y); nfr[i*8+3]=bfhi(r.y);
            nfr[i*8+4]=bflo(r.z); nfr[i*8+5]=bfhi(r.z);
            nfr[i*8+6]=bflo(r.w); nfr[i*8+7]=bfhi(r.w);
        }
    } else {
        const float4* q = (const float4*)((const float*)nfv + (size_t)n*40);
        #pragma unroll
        for (int i=0;i<10;i++){
            float4 t = q[i];
            nfr[i*4+0]=t.x; nfr[i*4+1]=t.y; nfr[i*4+2]=t.z; nfr[i*4+3]=t.w;
        }
    }
    float vals[40];
    #pragma unroll
    for (int w=0;w<16;w++){
        float mean = stats[w]*invN;
        float var  = fmaxf(stats[16+w]*invN - mean*mean, 0.0f);
        float is   = rsqrtf(var + BN_EPS_C) * rdv(bnws, w, fm);
        vals[w] = (s[w]-mean)*is + rdv(bnbs, w, fm) + nfr[w];
    }
    #pragma unroll
    for (int w=0;w<8;w++){
        float iv = rsqrtf(fmaxf(stats[32+w]*invN, 0.0f) + BN_EPS_C) * rdv(bnwv, w, fm);
        vals[16+w*3+0] = s[16+w*3+0]*iv + nfr[16+w*3+0];
        vals[16+w*3+1] = s[16+w*3+1]*iv + nfr[16+w*3+1];
        vals[16+w*3+2] = s[16+w*3+2]*iv + nfr[16+w*3+2];
    }
    if (!fm){
        u32 packed[20];
        #pragma unroll
        for (int q=0;q<20;q++) packed[q] = (u32)f2bf(vals[2*q]) | ((u32)f2bf(vals[2*q+1])<<16);
        uint4* op = (uint4*)((u16*)outv + (size_t)n*40);
        #pragma unroll
        for (int q=0;q<5;q++) op[q] = make_uint4(packed[q*4],packed[q*4+1],packed[q*4+2],packed[q*4+3]);
    } else {
        float4* op = (float4*)((float*)outv + (size_t)n*40);
        #pragma unroll
        for (int q=0;q<10;q++) op[q] = make_float4(vals[q*4],vals[q*4+1],vals[q*4+2],vals[q*4+3]);
    }
}

extern "C" void kernel_launch(void* const* d_in, const int* in_sizes, int n_in,
                              void* d_out, int out_size, void* d_ws, size_t ws_size,
                              hipStream_t stream)
{
    const void* nf     = d_in[0];
    const void* esh    = d_in[1];
    const void* ebasis = d_in[2];
    const int*  eidx   = (const int*)d_in[3];
    const void* W1 = d_in[4];
    const void* b1 = d_in[5];
    const void* W2 = d_in[6];
    const void* b2 = d_in[7];
    const void* W3 = d_in[8];
    const void* b3 = d_in[9];
    const void* si0 = d_in[10];
    const void* si1 = d_in[11];
    const void* bnws = d_in[12];
    const void* bnbs = d_in[13];
    const void* bnwv = d_in[14];

    float* ws    = (float*)d_ws;
    float* stats = ws + OFF_STATS;
    float* agg   = ws + OFF_AGG;

    if (ws_size < REQ_WS_BYTES){
        int nw = out_size/2;
        fill_kernel<<<(nw+255)/256, 256, 0, stream>>>((u32*)d_out, nw, 0x447A447Au);
        return;
    }

    hipMemsetAsync(stats, 0, 48*sizeof(float), stream);
    hipMemsetAsync(agg, 0, (size_t)2400000*sizeof(float), stream);
    detect_kernel<<<1, 64, 0, stream>>>((const u32*)nf, (u32*)(ws + OFF_FLAG));
    prep_kernel<<<407, 256, 0, stream>>>(W1,b1,W2,b2,W3,b3,si0,si1, ws);
    edge_kernel<<<(N_EDGES_C+127)/128, 128, 0, stream>>>(nf, esh, ebasis, eidx, ws, agg);
    node_kernel<<<(N_NODES_C+255)/256, 256, 0, stream>>>(ws, agg, stats);
    final_kernel<<<(N_NODES_C+255)/256, 256, 0, stream>>>(ws, agg, nf, bnws, bnbs, bnwv, d_out);
}

// Round 9
// 1238.210 us; speedup vs baseline: 1.9193x; 1.0293x over previous
//
#include <hip/hip_runtime.h>
#include <hip/hip_bf16.h>

// InteractionBlock: per-edge radial MLP (8->64->64->768) + tensor product
// contraction + scatter-sum + self-interaction + batchnorm epilogue.
// Round 9: probe removed (m89 D-layout HW-verified in round 8), single-wave
// 64-thread blocks (barriers never wait), tpb[edge][49] (conflict-free reads),
// cross-chunk register double-buffer of B fragments. LDS 21.8KB -> ~7 blk/CU.

#define N_NODES_C 50000
#define N_EDGES_C 300000
#define ALPHA_C 0.20412414523193154f   // 1/sqrt(24)
#define INV_SQRT3_C 0.5773502691896258f
#define BN_EPS_C 1e-5f

typedef unsigned int u32;
typedef unsigned long long u64;
typedef unsigned short u16;
typedef __attribute__((ext_vector_type(8))) short bf16x8;
typedef __attribute__((ext_vector_type(4))) float f32x4;

// workspace layout (float offsets) — total 2,455,040 floats = 9,820,160 B
#define OFF_STATS 0u            // 40
#define OFF_FLAG  48u           // u32 dtype flag
#define OFF_W3T   64u           // 49152 floats: frag-packed W3 bf16 hi + lo
#define OFF_W1T   49216u        // 512
#define OFF_B1    49728u        // 64
#define OFF_W2T   49792u        // 4096
#define OFF_B2    53888u        // 64
#define OFF_B3    53952u        // 768
#define OFF_SI0   54720u        // 256
#define OFF_SI1   54976u        // 64
#define OFF_AGG   55040u        // 50000*48 = 2,400,000 (svb reuses in place)
#define REQ_WS_BYTES ((size_t)(55040u + 2400000u) * 4u)

__device__ __forceinline__ float bflo(u32 u){ union{u32 i; float f;} c; c.i = u<<16; return c.f; }
__device__ __forceinline__ float bfhi(u32 u){ union{u32 i; float f;} c; c.i = u & 0xffff0000u; return c.f; }
__device__ __forceinline__ float b2f(__hip_bfloat16 b){ return (float)b; }
__device__ __forceinline__ u16 f2bf(float f){
    union{float f; u32 i;} c; c.f = f;
    u32 r = c.i + 0x7fffu + ((c.i>>16)&1u);
    return (u16)(r>>16);
}
__device__ __forceinline__ float sigmoidf_(float x){ return 1.0f/(1.0f+__expf(-x)); }
__device__ __forceinline__ float siluf_(float x){ return x*sigmoidf_(x); }
__device__ __forceinline__ float rdv(const void* p, int idx, bool fm){
    return fm ? ((const float*)p)[idx] : b2f(((const __hip_bfloat16*)p)[idx]);
}
__device__ __forceinline__ float sel4(float a, float b, float c, float d, int q){
    float lo = (q&1) ? b : a;
    float hi = (q&1) ? d : c;
    return (q&2) ? hi : lo;
}
__device__ __forceinline__ float sel8(float a0,float a1,float a2,float a3,
                                      float a4,float a5,float a6,float a7,int q){
    float x0=(q&1)?a1:a0, x1=(q&1)?a3:a2, x2=(q&1)?a5:a4, x3=(q&1)?a7:a6;
    float y0=(q&2)?x1:x0, y1=(q&2)?x3:x2;
    return (q&4)?y1:y0;
}

// ---------------- detect dtype ----------------
__global__ void detect_kernel(const u32* __restrict__ nfw, u32* __restrict__ flagp){
    int t = threadIdx.x;
    u32 w = nfw[t];
    int bad = 0;
    u32 lo = w & 0xffffu, hi = w >> 16;
    u32 elo = (lo >> 7) & 0xffu, ehi = (hi >> 7) & 0xffu;
    if (!(lo == 0u || (elo >= 90u && elo <= 140u))) bad++;
    if (!(hi == 0u || (ehi >= 90u && ehi <= 140u))) bad++;
    for (int off=32; off; off>>=1) bad += __shfl_down(bad, off);
    if (t == 0) flagp[0] = (bad >= 8) ? 1u : 0u;
}

__global__ __launch_bounds__(256) void fill_kernel(u32* __restrict__ p, int n, u32 v){
    int i = blockIdx.x*256 + threadIdx.x;
    if (i < n) p[i] = v;
}

// ---------------- prep ----------------
__global__ __launch_bounds__(256) void prep_kernel(
    const void* __restrict__ W1, const void* __restrict__ b1,
    const void* __restrict__ W2, const void* __restrict__ b2,
    const void* __restrict__ W3, const void* __restrict__ b3,
    const void* __restrict__ si0, const void* __restrict__ si1,
    float* __restrict__ ws)
{
    const bool fm = ((const u32*)(ws + OFF_FLAG))[0] != 0u;
    int i = blockIdx.x*256 + threadIdx.x;
    if (i < 49152){
        int j = i & 7, lane = (i>>3)&63, kh = (i>>9)&1, nt = i>>10;
        int n = lane & 15, qd = lane >> 4;
        int k = kh*32 + qd*8 + j;
        int col = nt*16 + n;
        float v = rdv(W3, k*768 + col, fm);
        u16 hv = f2bf(v);
        float hf = bflo((u32)hv);
        u16 lv = f2bf(v - hf);
        u16* BH = (u16*)(ws + OFF_W3T);
        BH[i] = hv;
        BH[49152 + i] = lv;
        return;
    }
    i -= 49152;
    if (i < 512){ int j=i>>3, t=i&7; ws[OFF_W1T+i] = rdv(W1, t*64+j, fm); return; }
    i -= 512;
    if (i < 64){ ws[OFF_B1+i] = rdv(b1, i, fm); return; }
    i -= 64;
    if (i < 4096){ int j=i>>6, k=i&63; ws[OFF_W2T+i] = rdv(W2, k*64+j, fm); return; }
    i -= 4096;
    if (i < 64){ ws[OFF_B2+i] = rdv(b2, i, fm); return; }
    i -= 64;
    if (i < 768){ ws[OFF_B3+i] = rdv(b3, i, fm); return; }
    i -= 768;
    if (i < 256){ int w=i>>4, u=i&15; ws[OFF_SI0+i] = rdv(si0, u*16+w, fm)*0.25f; return; }
    i -= 256;
    if (i < 64){ int w=i>>3, u=i&7; ws[OFF_SI1+i] = rdv(si1, u*8+w, fm)*0.35355339059327373f; return; }
}

// ---------------- edge kernel (single-wave blocks) ----------------
__global__ __launch_bounds__(64) void edge_kernel(
    const void* __restrict__ nfv,
    const void* __restrict__ eshv,
    const void* __restrict__ ebv,
    const int* __restrict__ eidx,
    const float* __restrict__ ws,
    float* __restrict__ agg)
{
    __shared__ __align__(16) u16   h2hi[64][72];   //  9216 B (stride 72 u16 = 144 B, 16B-aligned rows)
    __shared__ __align__(16) float tpb[64][49];    // 12544 B (reads (17*lane+c)%32: conflict-free)

    const bool fm = ((const u32*)(ws + OFF_FLAG))[0] != 0u;
    const int lane = threadIdx.x;
    const int m    = lane & 15;
    const int quad = lane >> 4;
    const int e    = blockIdx.x*64 + lane;
    const bool act = e < N_EDGES_C;

    // ---- inputs (dtype-dispatched; verified rounds 3/8) ----
    float sh0=0.f, sh1x=0.f, sh1y=0.f, sh1z=0.f;
    float f[40];
    float bas[8];
    #pragma unroll
    for (int i=0;i<40;i++) f[i]=0.f;
    #pragma unroll
    for (int i=0;i<8;i++) bas[i]=0.f;
    if (act){
        const int src = eidx[e];
        if (!fm){
            const u32* p = (const u32*)((const __hip_bfloat16*)eshv + (size_t)e*4);
            u32 a = p[0], b = p[1];
            sh0 = bflo(a); sh1x = bfhi(a); sh1y = bflo(b); sh1z = bfhi(b);
            const uint4* qq = (const uint4*)((const __hip_bfloat16*)nfv + (size_t)src*40);
            #pragma unroll
            for (int i=0;i<5;i++){
                uint4 r = qq[i];
                f[i*8+0]=bflo(r.x); f[i*8+1]=bfhi(r.x);
                f[i*8+2]=bflo(r.y); f[i*8+3]=bfhi(r.y);
                f[i*8+4]=bflo(r.z); f[i*8+5]=bfhi(r.z);
                f[i*8+6]=bflo(r.w); f[i*8+7]=bfhi(r.w);
            }
            uint4 r = *(const uint4*)((const __hip_bfloat16*)ebv + (size_t)e*8);
            bas[0]=bflo(r.x); bas[1]=bfhi(r.x); bas[2]=bflo(r.y); bas[3]=bfhi(r.y);
            bas[4]=bflo(r.z); bas[5]=bfhi(r.z); bas[6]=bflo(r.w); bas[7]=bfhi(r.w);
        } else {
            float4 r = *(const float4*)((const float*)eshv + (size_t)e*4);
            sh0 = r.x; sh1x = r.y; sh1y = r.z; sh1z = r.w;
            const float4* qq = (const float4*)((const float*)nfv + (size_t)src*40);
            #pragma unroll
            for (int i=0;i<10;i++){
                float4 t = qq[i];
                f[i*4+0]=t.x; f[i*4+1]=t.y; f[i*4+2]=t.z; f[i*4+3]=t.w;
            }
            const float4* qb = (const float4*)((const float*)ebv + (size_t)e*8);
            float4 t0 = qb[0], t1 = qb[1];
            bas[0]=t0.x; bas[1]=t0.y; bas[2]=t0.z; bas[3]=t0.w;
            bas[4]=t1.x; bas[5]=t1.y; bas[6]=t1.z; bas[7]=t1.w;
        }
    }

    // ---- MLP1 (W1T via wave-uniform s_loads) ----
    const float* W1T = ws + OFF_W1T;
    const float* b1f = ws + OFF_B1;
    float h1[64];
    #pragma unroll
    for (int j=0;j<64;j++){
        const float* w = W1T + j*8;
        float t0 = b1f[j] + bas[0]*w[0] + bas[4]*w[4];
        float t1 = bas[1]*w[1] + bas[5]*w[5];
        float t2 = bas[2]*w[2] + bas[6]*w[6];
        float t3 = bas[3]*w[3] + bas[7]*w[7];
        h1[j] = siluf_((t0+t1)+(t2+t3));
    }

    // ---- MLP2 -> bf16 h2 rows in LDS ----
    const float* W2T = ws + OFF_W2T;
    const float* b2f = ws + OFF_B2;
    #pragma unroll 1
    for (int j=0;j<64;j++){
        const float* w = W2T + j*64;
        float t0=b2f[j], t1=0.f, t2=0.f, t3=0.f;
        #pragma unroll
        for (int k=0;k<64;k+=4){
            t0 += h1[k]*w[k];     t1 += h1[k+1]*w[k+1];
            t2 += h1[k+2]*w[k+2]; t3 += h1[k+3]*w[k+3];
        }
        h2hi[lane][j] = f2bf(siluf_((t0+t1)+(t2+t3)));
    }
    __syncthreads();   // single wave: never waits, just orders LDS

    // ---- A fragments (all 4 g-tiles, both k-halves) ----
    bf16x8 Afr[4][2];
    #pragma unroll
    for (int g=0;g<4;g++){
        Afr[g][0] = *(const bf16x8*)&h2hi[g*16+m][quad*8];
        Afr[g][1] = *(const bf16x8*)&h2hi[g*16+m][32 + quad*8];
    }

    // ---- per-thread contraction coefficients ----
    float cssx[16], vxsh0[24], dvv[8];
    #pragma unroll
    for (int u=0;u<16;u++) cssx[u] = f[u]*sh0;
    #pragma unroll
    for (int j=0;j<24;j++) vxsh0[j] = f[16+j]*sh0;
    #pragma unroll
    for (int u=0;u<8;u++)
        dvv[u] = (f[16+u*3]*sh1x + f[17+u*3]*sh1y + f[18+u*3]*sh1z)*INV_SQRT3_C;

    float outs[24], tsv[8], av0[8], av1[8], av2[8];
    #pragma unroll
    for (int t=0;t<24;t++) outs[t]=0.f;
    #pragma unroll
    for (int t=0;t<8;t++){ tsv[t]=0.f; av0[t]=0.f; av1[t]=0.f; av2[t]=0.f; }

    const short* BH = (const short*)(ws + OFF_W3T);
    const short* BL = BH + 49152;
    const float* b3f = ws + OFF_B3;

    auto loadB = [&](bf16x8* dst, int cc2){
        #pragma unroll
        for (int ntl=0; ntl<3; ntl++){
            const int nt = cc2*3 + ntl;
            dst[ntl*4+0] = *(const bf16x8*)(BH + ((nt*2+0)*64 + lane)*8);
            dst[ntl*4+1] = *(const bf16x8*)(BL + ((nt*2+0)*64 + lane)*8);
            dst[ntl*4+2] = *(const bf16x8*)(BH + ((nt*2+1)*64 + lane)*8);
            dst[ntl*4+3] = *(const bf16x8*)(BL + ((nt*2+1)*64 + lane)*8);
        }
    };

    bf16x8 Bcur[12], Bnxt[12];
    loadB(Bcur, 0);

    #pragma unroll 1
    for (int cc=0; cc<16; cc++){
        if (cc < 15) loadB(Bnxt, cc+1);   // overlap next chunk's L2 latency

        // ---- phase 1: MFMA 48 cols -> tpb[edge][col] ----
        #pragma unroll
        for (int ntl=0; ntl<3; ntl++){
            #pragma unroll
            for (int g=0; g<4; g++){
                f32x4 acc = {0.f,0.f,0.f,0.f};
                acc = __builtin_amdgcn_mfma_f32_16x16x32_bf16(Afr[g][0], Bcur[ntl*4+0], acc, 0,0,0);
                acc = __builtin_amdgcn_mfma_f32_16x16x32_bf16(Afr[g][0], Bcur[ntl*4+1], acc, 0,0,0);
                acc = __builtin_amdgcn_mfma_f32_16x16x32_bf16(Afr[g][1], Bcur[ntl*4+2], acc, 0,0,0);
                acc = __builtin_amdgcn_mfma_f32_16x16x32_bf16(Afr[g][1], Bcur[ntl*4+3], acc, 0,0,0);
                // D (m89, HW-verified r8): row(edge-in-tile)=quad*4+r, col=m
                #pragma unroll
                for (int r=0;r<4;r++) tpb[g*16+quad*4+r][ntl*16+m] = acc[r];
            }
        }
        __syncthreads();

        // ---- phase 2: per-thread accumulate (lane = edge) ----
        float vals[48];
        #pragma unroll
        for (int c=0;c<48;c++) vals[c] = tpb[lane][c] + b3f[cc*48+c];

        if (cc < 8){              // ss: u = cc*2 + (c>=24), coeff sx[u]*sh0
            float cA = sel8(cssx[0],cssx[2],cssx[4],cssx[6],cssx[8],cssx[10],cssx[12],cssx[14], cc);
            float cB = sel8(cssx[1],cssx[3],cssx[5],cssx[7],cssx[9],cssx[11],cssx[13],cssx[15], cc);
            #pragma unroll
            for (int c=0;c<24;c++) outs[c] += cA*vals[c];
            #pragma unroll
            for (int c=0;c<24;c++) outs[c] += cB*vals[24+c];
        } else if (cc < 12){      // vv: u = (cc-8)*2 + (c>=24), coeff dvv[u]
            int q = cc-8;
            float cA = sel4(dvv[0],dvv[2],dvv[4],dvv[6], q);
            float cB = sel4(dvv[1],dvv[3],dvv[5],dvv[7], q);
            #pragma unroll
            for (int c=0;c<24;c++) outs[c] += cA*vals[c];
            #pragma unroll
            for (int c=0;c<24;c++) outs[c] += cB*vals[24+c];
        } else if (cc == 12){     // sv u=0..5
            #pragma unroll
            for (int c=0;c<48;c++) tsv[c&7] += f[c>>3]*vals[c];
        } else if (cc == 13){     // sv u=6..11
            #pragma unroll
            for (int c=0;c<48;c++) tsv[c&7] += f[6+(c>>3)]*vals[c];
        } else if (cc == 14){     // sv u=12..15 then vs u=0..1
            #pragma unroll
            for (int c=0;c<32;c++) tsv[c&7] += f[12+(c>>3)]*vals[c];
            #pragma unroll
            for (int c=32;c<48;c++){
                const int u=(c-32)>>3, w=(c-32)&7;
                av0[w] += vxsh0[u*3+0]*vals[c];
                av1[w] += vxsh0[u*3+1]*vals[c];
                av2[w] += vxsh0[u*3+2]*vals[c];
            }
        } else {                  // vs u=2..7
            #pragma unroll
            for (int c=0;c<48;c++){
                const int u=2+(c>>3), w=c&7;
                av0[w] += vxsh0[u*3+0]*vals[c];
                av1[w] += vxsh0[u*3+1]*vals[c];
                av2[w] += vxsh0[u*3+2]*vals[c];
            }
        }
        __syncthreads();

        #pragma unroll
        for (int i=0;i<12;i++) Bcur[i] = Bnxt[i];
    }

    // ---- per-thread atomics (own edge) ----
    if (act){
        const int dst = eidx[N_EDGES_C + e];
        float* dp = agg + (size_t)dst*48;
        #pragma unroll
        for (int w=0;w<24;w++) atomicAdd(dp+w, outs[w]*ALPHA_C);
        #pragma unroll
        for (int w=0;w<8;w++){
            atomicAdd(dp+24+w*3+0, (tsv[w]*sh1x + av0[w])*ALPHA_C);
            atomicAdd(dp+24+w*3+1, (tsv[w]*sh1y + av1[w])*ALPHA_C);
            atomicAdd(dp+24+w*3+2, (tsv[w]*sh1z + av2[w])*ALPHA_C);
        }
    }
}

// ---------------- node kernel ----------------
__global__ __launch_bounds__(256) void node_kernel(
    const float* __restrict__ ws,
    float* __restrict__ agg,
    float* __restrict__ stats)
{
    const float* si0T = ws + OFF_SI0;
    const float* si1T = ws + OFF_SI1;
    const int n = blockIdx.x*256 + threadIdx.x;
    const bool act = n < N_NODES_C;

    float a[48];
    if (act){
        const float4* p = (const float4*)(agg + (size_t)n*48);
        #pragma unroll
        for (int q=0;q<12;q++){ float4 r=p[q]; a[q*4]=r.x; a[q*4+1]=r.y; a[q*4+2]=r.z; a[q*4+3]=r.w; }
    } else {
        #pragma unroll
        for (int j=0;j<48;j++) a[j]=0.f;
    }
    float spre[16];
    #pragma unroll
    for (int u=0;u<16;u++) spre[u]=siluf_(a[u]);
    float v[24];
    #pragma unroll
    for (int u=0;u<8;u++){
        float g = sigmoidf_(a[16+u]);
        v[u*3+0]=a[24+u*3+0]*g; v[u*3+1]=a[24+u*3+1]*g; v[u*3+2]=a[24+u*3+2]*g;
    }
    float so[16];
    #pragma unroll
    for (int w=0;w<16;w++){
        const float* c = si0T + w*16;
        float t0=0.f,t1=0.f,t2=0.f,t3=0.f;
        #pragma unroll
        for (int u=0;u<16;u+=4){ t0+=spre[u]*c[u]; t1+=spre[u+1]*c[u+1]; t2+=spre[u+2]*c[u+2]; t3+=spre[u+3]*c[u+3]; }
        so[w]=(t0+t1)+(t2+t3);
    }
    float vo[24];
    #pragma unroll
    for (int w=0;w<8;w++){
        const float* c = si1T + w*8;
        float a0=0.f,a1=0.f,a2=0.f;
        #pragma unroll
        for (int u=0;u<8;u++){ a0+=v[u*3]*c[u]; a1+=v[u*3+1]*c[u]; a2+=v[u*3+2]*c[u]; }
        vo[w*3]=a0; vo[w*3+1]=a1; vo[w*3+2]=a2;
    }
    if (act){
        float4* op = (float4*)(agg + (size_t)n*48);
        op[0]=make_float4(so[0],so[1],so[2],so[3]);
        op[1]=make_float4(so[4],so[5],so[6],so[7]);
        op[2]=make_float4(so[8],so[9],so[10],so[11]);
        op[3]=make_float4(so[12],so[13],so[14],so[15]);
        #pragma unroll
        for (int q=0;q<6;q++) op[4+q]=make_float4(vo[q*4],vo[q*4+1],vo[q*4+2],vo[q*4+3]);
    }
    float r[40];
    #pragma unroll
    for (int w=0;w<16;w++){ r[w]=so[w]; r[16+w]=so[w]*so[w]; }
    #pragma unroll
    for (int w=0;w<8;w++) r[32+w]=(vo[w*3]*vo[w*3]+vo[w*3+1]*vo[w*3+1]+vo[w*3+2]*vo[w*3+2])*(1.0f/3.0f);
    #pragma unroll
    for (int j=0;j<40;j++){
        float x = r[j];
        for (int off=32; off; off>>=1) x += __shfl_down(x, off);
        r[j]=x;
    }
    if ((threadIdx.x & 63)==0){
        #pragma unroll
        for (int j=0;j<40;j++) atomicAdd(stats+j, r[j]);
    }
}

// ---------------- finalize ----------------
__global__ __launch_bounds__(256) void final_kernel(
    const float* __restrict__ ws, const float* __restrict__ svb,
    const void* __restrict__ nfv,
    const void* __restrict__ bnws, const void* __restrict__ bnbs,
    const void* __restrict__ bnwv,
    void* __restrict__ outv)
{
    const float* stats = ws + OFF_STATS;
    const bool fm = ((const u32*)(ws + OFF_FLAG))[0] != 0u;
    const int n = blockIdx.x*256 + threadIdx.x;
    if (n >= N_NODES_C) return;
    const float invN = 1.0f/(float)N_NODES_C;
    const float* s = svb + (size_t)n*48;
    float nfr[40];
    if (!fm){
        const uint4* q = (const uint4*)((const __hip_bfloat16*)nfv + (size_t)n*40);
        #pragma unroll
        for (int i=0;i<5;i++){
            uint4 r = q[i];
            nfr[i*8+0]=bflo(r.x); nfr[i*8+1]=bfhi(r.x);
            nfr[i*8+2]=bflo(r.y); nfr[i*8+3]=bfhi(r.y);
            nfr[i*8+4]=bflo(r.z); nfr[i*8+5]=bfhi(r.z);
            nfr[i*8+6]=bflo(r.w); nfr[i*8+7]=bfhi(r.w);
        }
    } else {
        const float4* q = (const float4*)((const float*)nfv + (size_t)n*40);
        #pragma unroll
        for (int i=0;i<10;i++){
            float4 t = q[i];
            nfr[i*4+0]=t.x; nfr[i*4+1]=t.y; nfr[i*4+2]=t.z; nfr[i*4+3]=t.w;
        }
    }
    float vals[40];
    #pragma unroll
    for (int w=0;w<16;w++){
        float mean = stats[w]*invN;
        float var  = fmaxf(stats[16+w]*invN - mean*mean, 0.0f);
        float is   = rsqrtf(var + BN_EPS_C) * rdv(bnws, w, fm);
        vals[w] = (s[w]-mean)*is + rdv(bnbs, w, fm) + nfr[w];
    }
    #pragma unroll
    for (int w=0;w<8;w++){
        float iv = rsqrtf(fmaxf(stats[32+w]*invN, 0.0f) + BN_EPS_C) * rdv(bnwv, w, fm);
        vals[16+w*3+0] = s[16+w*3+0]*iv + nfr[16+w*3+0];
        vals[16+w*3+1] = s[16+w*3+1]*iv + nfr[16+w*3+1];
        vals[16+w*3+2] = s[16+w*3+2]*iv + nfr[16+w*3+2];
    }
    if (!fm){
        u32 packed[20];
        #pragma unroll
        for (int q=0;q<20;q++) packed[q] = (u32)f2bf(vals[2*q]) | ((u32)f2bf(vals[2*q+1])<<16);
        uint4* op = (uint4*)((u16*)outv + (size_t)n*40);
        #pragma unroll
        for (int q=0;q<5;q++) op[q] = make_uint4(packed[q*4],packed[q*4+1],packed[q*4+2],packed[q*4+3]);
    } else {
        float4* op = (float4*)((float*)outv + (size_t)n*40);
        #pragma unroll
        for (int q=0;q<10;q++) op[q] = make_float4(vals[q*4],vals[q*4+1],vals[q*4+2],vals[q*4+3]);
    }
}

extern "C" void kernel_launch(void* const* d_in, const int* in_sizes, int n_in,
                              void* d_out, int out_size, void* d_ws, size_t ws_size,
                              hipStream_t stream)
{
    const void* nf     = d_in[0];
    const void* esh    = d_in[1];
    const void* ebasis = d_in[2];
    const int*  eidx   = (const int*)d_in[3];
    const void* W1 = d_in[4];
    const void* b1 = d_in[5];
    const void* W2 = d_in[6];
    const void* b2 = d_in[7];
    const void* W3 = d_in[8];
    const void* b3 = d_in[9];
    const void* si0 = d_in[10];
    const void* si1 = d_in[11];
    const void* bnws = d_in[12];
    const void* bnbs = d_in[13];
    const void* bnwv = d_in[14];

    float* ws    = (float*)d_ws;
    float* stats = ws + OFF_STATS;
    float* agg   = ws + OFF_AGG;

    if (ws_size < REQ_WS_BYTES){
        int nw = out_size/2;
        fill_kernel<<<(nw+255)/256, 256, 0, stream>>>((u32*)d_out, nw, 0x447A447Au);
        return;
    }

    hipMemsetAsync(stats, 0, 48*sizeof(float), stream);
    hipMemsetAsync(agg, 0, (size_t)2400000*sizeof(float), stream);
    detect_kernel<<<1, 64, 0, stream>>>((const u32*)nf, (u32*)(ws + OFF_FLAG));
    prep_kernel<<<215, 256, 0, stream>>>(W1,b1,W2,b2,W3,b3,si0,si1, ws);
    edge_kernel<<<(N_EDGES_C+63)/64, 64, 0, stream>>>(nf, esh, ebasis, eidx, ws, agg);
    node_kernel<<<(N_NODES_C+255)/256, 256, 0, stream>>>(ws, agg, stats);
    final_kernel<<<(N_NODES_C+255)/256, 256, 0, stream>>>(ws, agg, nf, bnws, bnbs, bnwv, d_out);
}

// Round 10
// 886.544 us; speedup vs baseline: 2.6806x; 1.3967x over previous
//
#include <hip/hip_runtime.h>
#include <hip/hip_bf16.h>

// InteractionBlock: per-edge radial MLP (8->64->64->768) + tensor product
// contraction + scatter-sum + self-interaction + batchnorm epilogue.
// Round 10: dst-counting-sort + message buffer replaces the 14.4M f32 agg
// atomics (theory: atomic RMW throughput ~16G/s is the wall; WRITE_SIZE 450MB
// invariant across r8/r9). Host branches on ws_size: sorted path needs ~69MB,
// else falls back to the verified round-9 atomic path.

#define N_NODES_C 50000
#define N_EDGES_C 300000
#define ALPHA_C 0.20412414523193154f   // 1/sqrt(24)
#define INV_SQRT3_C 0.5773502691896258f
#define BN_EPS_C 1e-5f

typedef unsigned int u32;
typedef unsigned long long u64;
typedef unsigned short u16;
typedef __attribute__((ext_vector_type(8))) short bf16x8;
typedef __attribute__((ext_vector_type(4))) float f32x4;

// workspace layout (float offsets)
#define OFF_STATS 0u            // 40
#define OFF_FLAG  48u           // u32 dtype flag
#define OFF_W3T   64u           // 49152 floats: frag-packed W3 bf16 hi + lo
#define OFF_W1T   49216u        // 512
#define OFF_B1    49728u        // 64
#define OFF_W2T   49792u        // 4096
#define OFF_B2    53888u        // 64
#define OFF_B3    53952u        // 768
#define OFF_SI0   54720u        // 256
#define OFF_SI1   54976u        // 64
#define OFF_AGG   55040u        // 50000*48 = 2,400,000 (svb in-place)
#define REQ_WS_BYTES ((size_t)(55040u + 2400000u) * 4u)
// sorted-path extras
#define OFF_DEG     2455040u    // 50000 ints
#define OFF_START   2505040u    // 50001 ints
#define OFF_CURSOR  2555044u    // 50000 ints
#define OFF_PERM    2605044u    // 300000 ints
#define OFF_MSG     2905044u    // 300000*48 floats (16B aligned)
#define REQ2_WS_BYTES ((size_t)(2905044u + 14400000u) * 4u)   // ~69.2 MB

__device__ __forceinline__ float bflo(u32 u){ union{u32 i; float f;} c; c.i = u<<16; return c.f; }
__device__ __forceinline__ float bfhi(u32 u){ union{u32 i; float f;} c; c.i = u & 0xffff0000u; return c.f; }
__device__ __forceinline__ float b2f(__hip_bfloat16 b){ return (float)b; }
__device__ __forceinline__ u16 f2bf(float f){
    union{float f; u32 i;} c; c.f = f;
    u32 r = c.i + 0x7fffu + ((c.i>>16)&1u);
    return (u16)(r>>16);
}
__device__ __forceinline__ float sigmoidf_(float x){ return 1.0f/(1.0f+__expf(-x)); }
__device__ __forceinline__ float siluf_(float x){ return x*sigmoidf_(x); }
__device__ __forceinline__ float rdv(const void* p, int idx, bool fm){
    return fm ? ((const float*)p)[idx] : b2f(((const __hip_bfloat16*)p)[idx]);
}
__device__ __forceinline__ float sel4(float a, float b, float c, float d, int q){
    float lo = (q&1) ? b : a;
    float hi = (q&1) ? d : c;
    return (q&2) ? hi : lo;
}
__device__ __forceinline__ float sel8(float a0,float a1,float a2,float a3,
                                      float a4,float a5,float a6,float a7,int q){
    float x0=(q&1)?a1:a0, x1=(q&1)?a3:a2, x2=(q&1)?a5:a4, x3=(q&1)?a7:a6;
    float y0=(q&2)?x1:x0, y1=(q&2)?x3:x2;
    return (q&4)?y1:y0;
}

// ---------------- detect dtype ----------------
__global__ void detect_kernel(const u32* __restrict__ nfw, u32* __restrict__ flagp){
    int t = threadIdx.x;
    u32 w = nfw[t];
    int bad = 0;
    u32 lo = w & 0xffffu, hi = w >> 16;
    u32 elo = (lo >> 7) & 0xffu, ehi = (hi >> 7) & 0xffu;
    if (!(lo == 0u || (elo >= 90u && elo <= 140u))) bad++;
    if (!(hi == 0u || (ehi >= 90u && ehi <= 140u))) bad++;
    for (int off=32; off; off>>=1) bad += __shfl_down(bad, off);
    if (t == 0) flagp[0] = (bad >= 8) ? 1u : 0u;
}

__global__ __launch_bounds__(256) void fill_kernel(u32* __restrict__ p, int n, u32 v){
    int i = blockIdx.x*256 + threadIdx.x;
    if (i < n) p[i] = v;
}

// ---------------- prep ----------------
__global__ __launch_bounds__(256) void prep_kernel(
    const void* __restrict__ W1, const void* __restrict__ b1,
    const void* __restrict__ W2, const void* __restrict__ b2,
    const void* __restrict__ W3, const void* __restrict__ b3,
    const void* __restrict__ si0, const void* __restrict__ si1,
    float* __restrict__ ws)
{
    const bool fm = ((const u32*)(ws + OFF_FLAG))[0] != 0u;
    int i = blockIdx.x*256 + threadIdx.x;
    if (i < 49152){
        int j = i & 7, lane = (i>>3)&63, kh = (i>>9)&1, nt = i>>10;
        int n = lane & 15, qd = lane >> 4;
        int k = kh*32 + qd*8 + j;
        int col = nt*16 + n;
        float v = rdv(W3, k*768 + col, fm);
        u16 hv = f2bf(v);
        float hf = bflo((u32)hv);
        u16 lv = f2bf(v - hf);
        u16* BH = (u16*)(ws + OFF_W3T);
        BH[i] = hv;
        BH[49152 + i] = lv;
        return;
    }
    i -= 49152;
    if (i < 512){ int j=i>>3, t=i&7; ws[OFF_W1T+i] = rdv(W1, t*64+j, fm); return; }
    i -= 512;
    if (i < 64){ ws[OFF_B1+i] = rdv(b1, i, fm); return; }
    i -= 64;
    if (i < 4096){ int j=i>>6, k=i&63; ws[OFF_W2T+i] = rdv(W2, k*64+j, fm); return; }
    i -= 4096;
    if (i < 64){ ws[OFF_B2+i] = rdv(b2, i, fm); return; }
    i -= 64;
    if (i < 768){ ws[OFF_B3+i] = rdv(b3, i, fm); return; }
    i -= 768;
    if (i < 256){ int w=i>>4, u=i&15; ws[OFF_SI0+i] = rdv(si0, u*16+w, fm)*0.25f; return; }
    i -= 256;
    if (i < 64){ int w=i>>3, u=i&7; ws[OFF_SI1+i] = rdv(si1, u*8+w, fm)*0.35355339059327373f; return; }
}

// ---------------- sort: count / scan / scatter ----------------
__global__ __launch_bounds__(256) void count_kernel(const int* __restrict__ dst, int* __restrict__ deg){
    int i = blockIdx.x*256 + threadIdx.x;
    if (i < N_EDGES_C) atomicAdd(&deg[dst[i]], 1);
}

__global__ __launch_bounds__(1024) void scan_kernel(const int* __restrict__ deg,
                                                    int* __restrict__ start,
                                                    int* __restrict__ cursor){
    __shared__ int buf[2][1024];
    const int t = threadIdx.x;
    const int c0 = t*49;
    int local = 0;
    #pragma unroll 1
    for (int i=0;i<49;i++){ int idx=c0+i; if (idx<N_NODES_C) local += deg[idx]; }
    buf[0][t] = local;
    __syncthreads();
    int src=0;
    for (int off=1; off<1024; off<<=1){
        int v = buf[src][t];
        if (t>=off) v += buf[src][t-off];
        buf[src^1][t]=v;
        src^=1;
        __syncthreads();
    }
    int off = (t==0)?0:buf[src][t-1];
    #pragma unroll 1
    for (int i=0;i<49;i++){
        int idx=c0+i;
        if (idx<N_NODES_C){ start[idx]=off; cursor[idx]=off; off+=deg[idx]; }
    }
    if (t==0) start[N_NODES_C]=buf[src][1023];
}

__global__ __launch_bounds__(256) void scatter_kernel(const int* __restrict__ dst,
                                                      int* __restrict__ cursor,
                                                      int* __restrict__ perm){
    int i = blockIdx.x*256 + threadIdx.x;
    if (i < N_EDGES_C){
        int p = atomicAdd(&cursor[dst[i]], 1);
        perm[p] = i;
    }
}

// ---------------- edge kernel (single-wave blocks; templated epilogue) ----------------
template<bool SORTED>
__global__ __launch_bounds__(64) void edge_kernel_t(
    const void* __restrict__ nfv,
    const void* __restrict__ eshv,
    const void* __restrict__ ebv,
    const int* __restrict__ eidx,
    const float* __restrict__ ws,
    const int* __restrict__ perm,
    float* __restrict__ outbuf)      // SORTED: msg[300K][48] ; else: agg[50K][48]
{
    __shared__ __align__(16) u16   h2hi[64][72];
    __shared__ __align__(16) float tpb[64][49];

    const bool fm = ((const u32*)(ws + OFF_FLAG))[0] != 0u;
    const int lane = threadIdx.x;
    const int m    = lane & 15;
    const int quad = lane >> 4;
    const int e    = blockIdx.x*64 + lane;
    const bool act = e < N_EDGES_C;
    const int es   = SORTED ? (act ? perm[e] : 0) : e;

    // ---- inputs (dtype-dispatched; verified rounds 3/8/9) ----
    float sh0=0.f, sh1x=0.f, sh1y=0.f, sh1z=0.f;
    float f[40];
    float bas[8];
    #pragma unroll
    for (int i=0;i<40;i++) f[i]=0.f;
    #pragma unroll
    for (int i=0;i<8;i++) bas[i]=0.f;
    if (act){
        const int src = eidx[es];
        if (!fm){
            const u32* p = (const u32*)((const __hip_bfloat16*)eshv + (size_t)es*4);
            u32 a = p[0], b = p[1];
            sh0 = bflo(a); sh1x = bfhi(a); sh1y = bflo(b); sh1z = bfhi(b);
            const uint4* qq = (const uint4*)((const __hip_bfloat16*)nfv + (size_t)src*40);
            #pragma unroll
            for (int i=0;i<5;i++){
                uint4 r = qq[i];
                f[i*8+0]=bflo(r.x); f[i*8+1]=bfhi(r.x);
                f[i*8+2]=bflo(r.y); f[i*8+3]=bfhi(r.y);
                f[i*8+4]=bflo(r.z); f[i*8+5]=bfhi(r.z);
                f[i*8+6]=bflo(r.w); f[i*8+7]=bfhi(r.w);
            }
            uint4 r = *(const uint4*)((const __hip_bfloat16*)ebv + (size_t)es*8);
            bas[0]=bflo(r.x); bas[1]=bfhi(r.x); bas[2]=bflo(r.y); bas[3]=bfhi(r.y);
            bas[4]=bflo(r.z); bas[5]=bfhi(r.z); bas[6]=bflo(r.w); bas[7]=bfhi(r.w);
        } else {
            float4 r = *(const float4*)((const float*)eshv + (size_t)es*4);
            sh0 = r.x; sh1x = r.y; sh1y = r.z; sh1z = r.w;
            const float4* qq = (const float4*)((const float*)nfv + (size_t)src*40);
            #pragma unroll
            for (int i=0;i<10;i++){
                float4 t = qq[i];
                f[i*4+0]=t.x; f[i*4+1]=t.y; f[i*4+2]=t.z; f[i*4+3]=t.w;
            }
            const float4* qb = (const float4*)((const float*)ebv + (size_t)es*8);
            float4 t0 = qb[0], t1 = qb[1];
            bas[0]=t0.x; bas[1]=t0.y; bas[2]=t0.z; bas[3]=t0.w;
            bas[4]=t1.x; bas[5]=t1.y; bas[6]=t1.z; bas[7]=t1.w;
        }
    }

    // ---- MLP1 ----
    const float* W1T = ws + OFF_W1T;
    const float* b1f = ws + OFF_B1;
    float h1[64];
    #pragma unroll
    for (int j=0;j<64;j++){
        const float* w = W1T + j*8;
        float t0 = b1f[j] + bas[0]*w[0] + bas[4]*w[4];
        float t1 = bas[1]*w[1] + bas[5]*w[5];
        float t2 = bas[2]*w[2] + bas[6]*w[6];
        float t3 = bas[3]*w[3] + bas[7]*w[7];
        h1[j] = siluf_((t0+t1)+(t2+t3));
    }

    // ---- MLP2 -> bf16 h2 rows in LDS ----
    const float* W2T = ws + OFF_W2T;
    const float* b2f = ws + OFF_B2;
    #pragma unroll 1
    for (int j=0;j<64;j++){
        const float* w = W2T + j*64;
        float t0=b2f[j], t1=0.f, t2=0.f, t3=0.f;
        #pragma unroll
        for (int k=0;k<64;k+=4){
            t0 += h1[k]*w[k];     t1 += h1[k+1]*w[k+1];
            t2 += h1[k+2]*w[k+2]; t3 += h1[k+3]*w[k+3];
        }
        h2hi[lane][j] = f2bf(siluf_((t0+t1)+(t2+t3)));
    }
    __syncthreads();

    // ---- A fragments ----
    bf16x8 Afr[4][2];
    #pragma unroll
    for (int g=0;g<4;g++){
        Afr[g][0] = *(const bf16x8*)&h2hi[g*16+m][quad*8];
        Afr[g][1] = *(const bf16x8*)&h2hi[g*16+m][32 + quad*8];
    }

    // ---- per-thread contraction coefficients ----
    float cssx[16], vxsh0[24], dvv[8];
    #pragma unroll
    for (int u=0;u<16;u++) cssx[u] = f[u]*sh0;
    #pragma unroll
    for (int j=0;j<24;j++) vxsh0[j] = f[16+j]*sh0;
    #pragma unroll
    for (int u=0;u<8;u++)
        dvv[u] = (f[16+u*3]*sh1x + f[17+u*3]*sh1y + f[18+u*3]*sh1z)*INV_SQRT3_C;

    float outs[24], tsv[8], av0[8], av1[8], av2[8];
    #pragma unroll
    for (int t=0;t<24;t++) outs[t]=0.f;
    #pragma unroll
    for (int t=0;t<8;t++){ tsv[t]=0.f; av0[t]=0.f; av1[t]=0.f; av2[t]=0.f; }

    const short* BH = (const short*)(ws + OFF_W3T);
    const short* BL = BH + 49152;
    const float* b3f = ws + OFF_B3;

    auto loadB = [&](bf16x8* dst2, int cc2){
        #pragma unroll
        for (int ntl=0; ntl<3; ntl++){
            const int nt = cc2*3 + ntl;
            dst2[ntl*4+0] = *(const bf16x8*)(BH + ((nt*2+0)*64 + lane)*8);
            dst2[ntl*4+1] = *(const bf16x8*)(BL + ((nt*2+0)*64 + lane)*8);
            dst2[ntl*4+2] = *(const bf16x8*)(BH + ((nt*2+1)*64 + lane)*8);
            dst2[ntl*4+3] = *(const bf16x8*)(BL + ((nt*2+1)*64 + lane)*8);
        }
    };

    bf16x8 Bcur[12], Bnxt[12];
    loadB(Bcur, 0);

    #pragma unroll 1
    for (int cc=0; cc<16; cc++){
        if (cc < 15) loadB(Bnxt, cc+1);

        #pragma unroll
        for (int ntl=0; ntl<3; ntl++){
            #pragma unroll
            for (int g=0; g<4; g++){
                f32x4 acc = {0.f,0.f,0.f,0.f};
                acc = __builtin_amdgcn_mfma_f32_16x16x32_bf16(Afr[g][0], Bcur[ntl*4+0], acc, 0,0,0);
                acc = __builtin_amdgcn_mfma_f32_16x16x32_bf16(Afr[g][0], Bcur[ntl*4+1], acc, 0,0,0);
                acc = __builtin_amdgcn_mfma_f32_16x16x32_bf16(Afr[g][1], Bcur[ntl*4+2], acc, 0,0,0);
                acc = __builtin_amdgcn_mfma_f32_16x16x32_bf16(Afr[g][1], Bcur[ntl*4+3], acc, 0,0,0);
                #pragma unroll
                for (int r=0;r<4;r++) tpb[g*16+quad*4+r][ntl*16+m] = acc[r];
            }
        }
        __syncthreads();

        float vals[48];
        #pragma unroll
        for (int c=0;c<48;c++) vals[c] = tpb[lane][c] + b3f[cc*48+c];

        if (cc < 8){
            float cA = sel8(cssx[0],cssx[2],cssx[4],cssx[6],cssx[8],cssx[10],cssx[12],cssx[14], cc);
            float cB = sel8(cssx[1],cssx[3],cssx[5],cssx[7],cssx[9],cssx[11],cssx[13],cssx[15], cc);
            #pragma unroll
            for (int c=0;c<24;c++) outs[c] += cA*vals[c];
            #pragma unroll
            for (int c=0;c<24;c++) outs[c] += cB*vals[24+c];
        } else if (cc < 12){
            int q = cc-8;
            float cA = sel4(dvv[0],dvv[2],dvv[4],dvv[6], q);
            float cB = sel4(dvv[1],dvv[3],dvv[5],dvv[7], q);
            #pragma unroll
            for (int c=0;c<24;c++) outs[c] += cA*vals[c];
            #pragma unroll
            for (int c=0;c<24;c++) outs[c] += cB*vals[24+c];
        } else if (cc == 12){
            #pragma unroll
            for (int c=0;c<48;c++) tsv[c&7] += f[c>>3]*vals[c];
        } else if (cc == 13){
            #pragma unroll
            for (int c=0;c<48;c++) tsv[c&7] += f[6+(c>>3)]*vals[c];
        } else if (cc == 14){
            #pragma unroll
            for (int c=0;c<32;c++) tsv[c&7] += f[12+(c>>3)]*vals[c];
            #pragma unroll
            for (int c=32;c<48;c++){
                const int u=(c-32)>>3, w=(c-32)&7;
                av0[w] += vxsh0[u*3+0]*vals[c];
                av1[w] += vxsh0[u*3+1]*vals[c];
                av2[w] += vxsh0[u*3+2]*vals[c];
            }
        } else {
            #pragma unroll
            for (int c=0;c<48;c++){
                const int u=2+(c>>3), w=c&7;
                av0[w] += vxsh0[u*3+0]*vals[c];
                av1[w] += vxsh0[u*3+1]*vals[c];
                av2[w] += vxsh0[u*3+2]*vals[c];
            }
        }
        __syncthreads();

        #pragma unroll
        for (int i=0;i<12;i++) Bcur[i] = Bnxt[i];
    }

    if (act){
        if (SORTED){
            // plain stores to msg[e][48] (e = dst-sorted slot)
            float v48[48];
            #pragma unroll
            for (int w=0;w<24;w++) v48[w] = outs[w]*ALPHA_C;
            #pragma unroll
            for (int w=0;w<8;w++){
                v48[24+w*3+0] = (tsv[w]*sh1x + av0[w])*ALPHA_C;
                v48[24+w*3+1] = (tsv[w]*sh1y + av1[w])*ALPHA_C;
                v48[24+w*3+2] = (tsv[w]*sh1z + av2[w])*ALPHA_C;
            }
            float4* mp = (float4*)(outbuf + (size_t)e*48);
            #pragma unroll
            for (int q=0;q<12;q++) mp[q] = make_float4(v48[q*4],v48[q*4+1],v48[q*4+2],v48[q*4+3]);
        } else {
            const int dst = eidx[N_EDGES_C + e];
            float* dp = outbuf + (size_t)dst*48;
            #pragma unroll
            for (int w=0;w<24;w++) atomicAdd(dp+w, outs[w]*ALPHA_C);
            #pragma unroll
            for (int w=0;w<8;w++){
                atomicAdd(dp+24+w*3+0, (tsv[w]*sh1x + av0[w])*ALPHA_C);
                atomicAdd(dp+24+w*3+1, (tsv[w]*sh1y + av1[w])*ALPHA_C);
                atomicAdd(dp+24+w*3+2, (tsv[w]*sh1z + av2[w])*ALPHA_C);
            }
        }
    }
}

// ---------------- node kernel (templated source of agg) ----------------
template<bool SORTED>
__global__ __launch_bounds__(256) void node_kernel_t(
    const float* __restrict__ ws,
    const float* __restrict__ msg,     // SORTED only
    const int* __restrict__ start,     // SORTED only
    float* __restrict__ svb,           // agg region: read (atomic path) / write svb
    float* __restrict__ stats)
{
    const float* si0T = ws + OFF_SI0;
    const float* si1T = ws + OFF_SI1;
    const int n = blockIdx.x*256 + threadIdx.x;
    const bool act = n < N_NODES_C;

    float a[48];
    #pragma unroll
    for (int j=0;j<48;j++) a[j]=0.f;
    if (act){
        if (SORTED){
            int s = start[n], en = start[n+1];
            #pragma unroll 1
            for (int r=s; r<en; ++r){
                const float4* mp = (const float4*)(msg + (size_t)r*48);
                #pragma unroll
                for (int q=0;q<12;q++){
                    float4 t = mp[q];
                    a[q*4]+=t.x; a[q*4+1]+=t.y; a[q*4+2]+=t.z; a[q*4+3]+=t.w;
                }
            }
        } else {
            const float4* p = (const float4*)(svb + (size_t)n*48);
            #pragma unroll
            for (int q=0;q<12;q++){ float4 r=p[q]; a[q*4]=r.x; a[q*4+1]=r.y; a[q*4+2]=r.z; a[q*4+3]=r.w; }
        }
    }
    float spre[16];
    #pragma unroll
    for (int u=0;u<16;u++) spre[u]=siluf_(a[u]);
    float v[24];
    #pragma unroll
    for (int u=0;u<8;u++){
        float g = sigmoidf_(a[16+u]);
        v[u*3+0]=a[24+u*3+0]*g; v[u*3+1]=a[24+u*3+1]*g; v[u*3+2]=a[24+u*3+2]*g;
    }
    float so[16];
    #pragma unroll
    for (int w=0;w<16;w++){
        const float* c = si0T + w*16;
        float t0=0.f,t1=0.f,t2=0.f,t3=0.f;
        #pragma unroll
        for (int u=0;u<16;u+=4){ t0+=spre[u]*c[u]; t1+=spre[u+1]*c[u+1]; t2+=spre[u+2]*c[u+2]; t3+=spre[u+3]*c[u+3]; }
        so[w]=(t0+t1)+(t2+t3);
    }
    float vo[24];
    #pragma unroll
    for (int w=0;w<8;w++){
        const float* c = si1T + w*8;
        float a0=0.f,a1=0.f,a2=0.f;
        #pragma unroll
        for (int u=0;u<8;u++){ a0+=v[u*3]*c[u]; a1+=v[u*3+1]*c[u]; a2+=v[u*3+2]*c[u]; }
        vo[w*3]=a0; vo[w*3+1]=a1; vo[w*3+2]=a2;
    }
    if (act){
        float4* op = (float4*)(svb + (size_t)n*48);
        op[0]=make_float4(so[0],so[1],so[2],so[3]);
        op[1]=make_float4(so[4],so[5],so[6],so[7]);
        op[2]=make_float4(so[8],so[9],so[10],so[11]);
        op[3]=make_float4(so[12],so[13],so[14],so[15]);
        #pragma unroll
        for (int q=0;q<6;q++) op[4+q]=make_float4(vo[q*4],vo[q*4+1],vo[q*4+2],vo[q*4+3]);
    }
    float r[40];
    #pragma unroll
    for (int w=0;w<16;w++){ r[w]=so[w]; r[16+w]=so[w]*so[w]; }
    #pragma unroll
    for (int w=0;w<8;w++) r[32+w]=(vo[w*3]*vo[w*3]+vo[w*3+1]*vo[w*3+1]+vo[w*3+2]*vo[w*3+2])*(1.0f/3.0f);
    #pragma unroll
    for (int j=0;j<40;j++){
        float x = r[j];
        for (int off=32; off; off>>=1) x += __shfl_down(x, off);
        r[j]=x;
    }
    if ((threadIdx.x & 63)==0){
        #pragma unroll
        for (int j=0;j<40;j++) atomicAdd(stats+j, r[j]);
    }
}

// ---------------- finalize ----------------
__global__ __launch_bounds__(256) void final_kernel(
    const float* __restrict__ ws, const float* __restrict__ svb,
    const void* __restrict__ nfv,
    const void* __restrict__ bnws, const void* __restrict__ bnbs,
    const void* __restrict__ bnwv,
    void* __restrict__ outv)
{
    const float* stats = ws + OFF_STATS;
    const bool fm = ((const u32*)(ws + OFF_FLAG))[0] != 0u;
    const int n = blockIdx.x*256 + threadIdx.x;
    if (n >= N_NODES_C) return;
    const float invN = 1.0f/(float)N_NODES_C;
    const float* s = svb + (size_t)n*48;
    float nfr[40];
    if (!fm){
        const uint4* q = (const uint4*)((const __hip_bfloat16*)nfv + (size_t)n*40);
        #pragma unroll
        for (int i=0;i<5;i++){
            uint4 r = q[i];
            nfr[i*8+0]=bflo(r.x); nfr[i*8+1]=bfhi(r.x);
            nfr[i*8+2]=bflo(r.y); nfr[i*8+3]=bfhi(r.y);
            nfr[i*8+4]=bflo(r.z); nfr[i*8+5]=bfhi(r.z);
            nfr[i*8+6]=bflo(r.w); nfr[i*8+7]=bfhi(r.w);
        }
    } else {
        const float4* q = (const float4*)((const float*)nfv + (size_t)n*40);
        #pragma unroll
        for (int i=0;i<10;i++){
            float4 t = q[i];
            nfr[i*4+0]=t.x; nfr[i*4+1]=t.y; nfr[i*4+2]=t.z; nfr[i*4+3]=t.w;
        }
    }
    float vals[40];
    #pragma unroll
    for (int w=0;w<16;w++){
        float mean = stats[w]*invN;
        float var  = fmaxf(stats[16+w]*invN - mean*mean, 0.0f);
        float is   = rsqrtf(var + BN_EPS_C) * rdv(bnws, w, fm);
        vals[w] = (s[w]-mean)*is + rdv(bnbs, w, fm) + nfr[w];
    }
    #pragma unroll
    for (int w=0;w<8;w++){
        float iv = rsqrtf(fmaxf(stats[32+w]*invN, 0.0f) + BN_EPS_C) * rdv(bnwv, w, fm);
        vals[16+w*3+0] = s[16+w*3+0]*iv + nfr[16+w*3+0];
        vals[16+w*3+1] = s[16+w*3+1]*iv + nfr[16+w*3+1];
        vals[16+w*3+2] = s[16+w*3+2]*iv + nfr[16+w*3+2];
    }
    if (!fm){
        u32 packed[20];
        #pragma unroll
        for (int q=0;q<20;q++) packed[q] = (u32)f2bf(vals[2*q]) | ((u32)f2bf(vals[2*q+1])<<16);
        uint4* op = (uint4*)((u16*)outv + (size_t)n*40);
        #pragma unroll
        for (int q=0;q<5;q++) op[q] = make_uint4(packed[q*4],packed[q*4+1],packed[q*4+2],packed[q*4+3]);
    } else {
        float4* op = (float4*)((float*)outv + (size_t)n*40);
        #pragma unroll
        for (int q=0;q<10;q++) op[q] = make_float4(vals[q*4],vals[q*4+1],vals[q*4+2],vals[q*4+3]);
    }
}

extern "C" void kernel_launch(void* const* d_in, const int* in_sizes, int n_in,
                              void* d_out, int out_size, void* d_ws, size_t ws_size,
                              hipStream_t stream)
{
    const void* nf     = d_in[0];
    const void* esh    = d_in[1];
    const void* ebasis = d_in[2];
    const int*  eidx   = (const int*)d_in[3];
    const void* W1 = d_in[4];
    const void* b1 = d_in[5];
    const void* W2 = d_in[6];
    const void* b2 = d_in[7];
    const void* W3 = d_in[8];
    const void* b3 = d_in[9];
    const void* si0 = d_in[10];
    const void* si1 = d_in[11];
    const void* bnws = d_in[12];
    const void* bnbs = d_in[13];
    const void* bnwv = d_in[14];

    float* ws    = (float*)d_ws;
    float* stats = ws + OFF_STATS;
    float* agg   = ws + OFF_AGG;

    if (ws_size < REQ_WS_BYTES){
        int nw = out_size/2;
        fill_kernel<<<(nw+255)/256, 256, 0, stream>>>((u32*)d_out, nw, 0x447A447Au);
        return;
    }

    const int* dst = eidx + N_EDGES_C;
    const int EB = (N_EDGES_C+255)/256;

    hipMemsetAsync(stats, 0, 48*sizeof(float), stream);
    detect_kernel<<<1, 64, 0, stream>>>((const u32*)nf, (u32*)(ws + OFF_FLAG));
    prep_kernel<<<215, 256, 0, stream>>>(W1,b1,W2,b2,W3,b3,si0,si1, ws);

    if (ws_size >= REQ2_WS_BYTES){
        // ---- sorted (atomic-free aggregation) path ----
        int*   deg    = (int*)(ws + OFF_DEG);
        int*   startp = (int*)(ws + OFF_START);
        int*   cursor = (int*)(ws + OFF_CURSOR);
        int*   perm   = (int*)(ws + OFF_PERM);
        float* msg    = ws + OFF_MSG;

        hipMemsetAsync(deg, 0, N_NODES_C*sizeof(int), stream);
        count_kernel<<<EB, 256, 0, stream>>>(dst, deg);
        scan_kernel<<<1, 1024, 0, stream>>>(deg, startp, cursor);
        scatter_kernel<<<EB, 256, 0, stream>>>(dst, cursor, perm);
        edge_kernel_t<true><<<(N_EDGES_C+63)/64, 64, 0, stream>>>(nf, esh, ebasis, eidx, ws, perm, msg);
        node_kernel_t<true><<<(N_NODES_C+255)/256, 256, 0, stream>>>(ws, msg, startp, agg, stats);
    } else {
        // ---- fallback: round-9 verified atomic path ----
        hipMemsetAsync(agg, 0, (size_t)2400000*sizeof(float), stream);
        edge_kernel_t<false><<<(N_EDGES_C+63)/64, 64, 0, stream>>>(nf, esh, ebasis, eidx, ws, nullptr, agg);
        node_kernel_t<false><<<(N_NODES_C+255)/256, 256, 0, stream>>>(ws, nullptr, nullptr, agg, stats);
    }
    final_kernel<<<(N_NODES_C+255)/256, 256, 0, stream>>>(ws, agg, nf, bnws, bnbs, bnwv, d_out);
}

// Round 11
// 871.520 us; speedup vs baseline: 2.7268x; 1.0172x over previous
//
#include <hip/hip_runtime.h>
#include <hip/hip_bf16.h>

// InteractionBlock: per-edge radial MLP (8->64->64->768) + tensor product
// contraction + scatter-sum + self-interaction + batchnorm epilogue.
// Round 11: (a) edge kernel back to original edge order (coalesced esh/eb
// reads; FETCH +50MB in r10 was perm-gather over-fetch) writing msg[pos[e]]
// via inverse perm; (b) tpb overlays h2 LDS (dead after A-frag load):
// 22.0 -> 12.8 KB per block (occupancy evidence: resident ~ 64KB/LDS_block).

#define N_NODES_C 50000
#define N_EDGES_C 300000
#define ALPHA_C 0.20412414523193154f   // 1/sqrt(24)
#define INV_SQRT3_C 0.5773502691896258f
#define BN_EPS_C 1e-5f

typedef unsigned int u32;
typedef unsigned long long u64;
typedef unsigned short u16;
typedef __attribute__((ext_vector_type(8))) short bf16x8;
typedef __attribute__((ext_vector_type(4))) float f32x4;

// workspace layout (float offsets)
#define OFF_STATS 0u            // 40
#define OFF_FLAG  48u           // u32 dtype flag
#define OFF_W3T   64u           // 49152 floats: frag-packed W3 bf16 hi + lo
#define OFF_W1T   49216u        // 512
#define OFF_B1    49728u        // 64
#define OFF_W2T   49792u        // 4096
#define OFF_B2    53888u        // 64
#define OFF_B3    53952u        // 768
#define OFF_SI0   54720u        // 256
#define OFF_SI1   54976u        // 64
#define OFF_AGG   55040u        // 50000*48 = 2,400,000 (svb in-place)
#define REQ_WS_BYTES ((size_t)(55040u + 2400000u) * 4u)
// sorted-path extras
#define OFF_DEG     2455040u    // 50000 ints
#define OFF_START   2505040u    // 50001 ints
#define OFF_CURSOR  2555044u    // 50000 ints
#define OFF_POS     2605044u    // 300000 ints (inverse perm: edge -> sorted slot)
#define OFF_MSG     2905044u    // 300000*48 floats (16B aligned)
#define REQ2_WS_BYTES ((size_t)(2905044u + 14400000u) * 4u)   // ~69.2 MB

__device__ __forceinline__ float bflo(u32 u){ union{u32 i; float f;} c; c.i = u<<16; return c.f; }
__device__ __forceinline__ float bfhi(u32 u){ union{u32 i; float f;} c; c.i = u & 0xffff0000u; return c.f; }
__device__ __forceinline__ float b2f(__hip_bfloat16 b){ return (float)b; }
__device__ __forceinline__ u16 f2bf(float f){
    union{float f; u32 i;} c; c.f = f;
    u32 r = c.i + 0x7fffu + ((c.i>>16)&1u);
    return (u16)(r>>16);
}
__device__ __forceinline__ float sigmoidf_(float x){ return 1.0f/(1.0f+__expf(-x)); }
__device__ __forceinline__ float siluf_(float x){ return x*sigmoidf_(x); }
__device__ __forceinline__ float rdv(const void* p, int idx, bool fm){
    return fm ? ((const float*)p)[idx] : b2f(((const __hip_bfloat16*)p)[idx]);
}
__device__ __forceinline__ float sel4(float a, float b, float c, float d, int q){
    float lo = (q&1) ? b : a;
    float hi = (q&1) ? d : c;
    return (q&2) ? hi : lo;
}
__device__ __forceinline__ float sel8(float a0,float a1,float a2,float a3,
                                      float a4,float a5,float a6,float a7,int q){
    float x0=(q&1)?a1:a0, x1=(q&1)?a3:a2, x2=(q&1)?a5:a4, x3=(q&1)?a7:a6;
    float y0=(q&2)?x1:x0, y1=(q&2)?x3:x2;
    return (q&4)?y1:y0;
}

// ---------------- detect dtype ----------------
__global__ void detect_kernel(const u32* __restrict__ nfw, u32* __restrict__ flagp){
    int t = threadIdx.x;
    u32 w = nfw[t];
    int bad = 0;
    u32 lo = w & 0xffffu, hi = w >> 16;
    u32 elo = (lo >> 7) & 0xffu, ehi = (hi >> 7) & 0xffu;
    if (!(lo == 0u || (elo >= 90u && elo <= 140u))) bad++;
    if (!(hi == 0u || (ehi >= 90u && ehi <= 140u))) bad++;
    for (int off=32; off; off>>=1) bad += __shfl_down(bad, off);
    if (t == 0) flagp[0] = (bad >= 8) ? 1u : 0u;
}

__global__ __launch_bounds__(256) void fill_kernel(u32* __restrict__ p, int n, u32 v){
    int i = blockIdx.x*256 + threadIdx.x;
    if (i < n) p[i] = v;
}

// ---------------- prep ----------------
__global__ __launch_bounds__(256) void prep_kernel(
    const void* __restrict__ W1, const void* __restrict__ b1,
    const void* __restrict__ W2, const void* __restrict__ b2,
    const void* __restrict__ W3, const void* __restrict__ b3,
    const void* __restrict__ si0, const void* __restrict__ si1,
    float* __restrict__ ws)
{
    const bool fm = ((const u32*)(ws + OFF_FLAG))[0] != 0u;
    int i = blockIdx.x*256 + threadIdx.x;
    if (i < 49152){
        int j = i & 7, lane = (i>>3)&63, kh = (i>>9)&1, nt = i>>10;
        int n = lane & 15, qd = lane >> 4;
        int k = kh*32 + qd*8 + j;
        int col = nt*16 + n;
        float v = rdv(W3, k*768 + col, fm);
        u16 hv = f2bf(v);
        float hf = bflo((u32)hv);
        u16 lv = f2bf(v - hf);
        u16* BH = (u16*)(ws + OFF_W3T);
        BH[i] = hv;
        BH[49152 + i] = lv;
        return;
    }
    i -= 49152;
    if (i < 512){ int j=i>>3, t=i&7; ws[OFF_W1T+i] = rdv(W1, t*64+j, fm); return; }
    i -= 512;
    if (i < 64){ ws[OFF_B1+i] = rdv(b1, i, fm); return; }
    i -= 64;
    if (i < 4096){ int j=i>>6, k=i&63; ws[OFF_W2T+i] = rdv(W2, k*64+j, fm); return; }
    i -= 4096;
    if (i < 64){ ws[OFF_B2+i] = rdv(b2, i, fm); return; }
    i -= 64;
    if (i < 768){ ws[OFF_B3+i] = rdv(b3, i, fm); return; }
    i -= 768;
    if (i < 256){ int w=i>>4, u=i&15; ws[OFF_SI0+i] = rdv(si0, u*16+w, fm)*0.25f; return; }
    i -= 256;
    if (i < 64){ int w=i>>3, u=i&7; ws[OFF_SI1+i] = rdv(si1, u*8+w, fm)*0.35355339059327373f; return; }
}

// ---------------- sort: count / scan / pos-scatter ----------------
__global__ __launch_bounds__(256) void count_kernel(const int* __restrict__ dst, int* __restrict__ deg){
    int i = blockIdx.x*256 + threadIdx.x;
    if (i < N_EDGES_C) atomicAdd(&deg[dst[i]], 1);
}

__global__ __launch_bounds__(1024) void scan_kernel(const int* __restrict__ deg,
                                                    int* __restrict__ start,
                                                    int* __restrict__ cursor){
    __shared__ int buf[2][1024];
    const int t = threadIdx.x;
    const int c0 = t*49;
    int local = 0;
    #pragma unroll 1
    for (int i=0;i<49;i++){ int idx=c0+i; if (idx<N_NODES_C) local += deg[idx]; }
    buf[0][t] = local;
    __syncthreads();
    int src=0;
    for (int off=1; off<1024; off<<=1){
        int v = buf[src][t];
        if (t>=off) v += buf[src][t-off];
        buf[src^1][t]=v;
        src^=1;
        __syncthreads();
    }
    int off = (t==0)?0:buf[src][t-1];
    #pragma unroll 1
    for (int i=0;i<49;i++){
        int idx=c0+i;
        if (idx<N_NODES_C){ start[idx]=off; cursor[idx]=off; off+=deg[idx]; }
    }
    if (t==0) start[N_NODES_C]=buf[src][1023];
}

__global__ __launch_bounds__(256) void scatter_kernel(const int* __restrict__ dst,
                                                      int* __restrict__ cursor,
                                                      int* __restrict__ pos){
    int i = blockIdx.x*256 + threadIdx.x;
    if (i < N_EDGES_C){
        pos[i] = atomicAdd(&cursor[dst[i]], 1);
    }
}

// ---------------- edge kernel (single-wave blocks; overlay LDS) ----------------
template<bool SORTED>
__global__ __launch_bounds__(64) void edge_kernel_t(
    const void* __restrict__ nfv,
    const void* __restrict__ eshv,
    const void* __restrict__ ebv,
    const int* __restrict__ eidx,
    const float* __restrict__ ws,
    const int* __restrict__ pos,
    float* __restrict__ outbuf)      // SORTED: msg[300K][48] ; else: agg[50K][48]
{
    // union: h2 region (9216 B) is dead once A-fragments are in registers;
    // tpb (12544 B) overlays it.  LDS = 12544 B.
    __shared__ __align__(16) char uni[12544];
    u16   (*h2hi)[72] = (u16 (*)[72])uni;   // [64][72]
    float (*tpb)[49]  = (float (*)[49])uni; // [64][49]

    const bool fm = ((const u32*)(ws + OFF_FLAG))[0] != 0u;
    const int lane = threadIdx.x;
    const int m    = lane & 15;
    const int quad = lane >> 4;
    const int e    = blockIdx.x*64 + lane;
    const bool act = e < N_EDGES_C;
    const int slot = (SORTED && act) ? pos[e] : 0;   // early, coalesced

    // ---- inputs (original order: coalesced; verified rounds 3/8/9) ----
    float sh0=0.f, sh1x=0.f, sh1y=0.f, sh1z=0.f;
    float f[40];
    float bas[8];
    #pragma unroll
    for (int i=0;i<40;i++) f[i]=0.f;
    #pragma unroll
    for (int i=0;i<8;i++) bas[i]=0.f;
    if (act){
        const int src = eidx[e];
        if (!fm){
            const u32* p = (const u32*)((const __hip_bfloat16*)eshv + (size_t)e*4);
            u32 a = p[0], b = p[1];
            sh0 = bflo(a); sh1x = bfhi(a); sh1y = bflo(b); sh1z = bfhi(b);
            const uint4* qq = (const uint4*)((const __hip_bfloat16*)nfv + (size_t)src*40);
            #pragma unroll
            for (int i=0;i<5;i++){
                uint4 r = qq[i];
                f[i*8+0]=bflo(r.x); f[i*8+1]=bfhi(r.x);
                f[i*8+2]=bflo(r.y); f[i*8+3]=bfhi(r.y);
                f[i*8+4]=bflo(r.z); f[i*8+5]=bfhi(r.z);
                f[i*8+6]=bflo(r.w); f[i*8+7]=bfhi(r.w);
            }
            uint4 r = *(const uint4*)((const __hip_bfloat16*)ebv + (size_t)e*8);
            bas[0]=bflo(r.x); bas[1]=bfhi(r.x); bas[2]=bflo(r.y); bas[3]=bfhi(r.y);
            bas[4]=bflo(r.z); bas[5]=bfhi(r.z); bas[6]=bflo(r.w); bas[7]=bfhi(r.w);
        } else {
            float4 r = *(const float4*)((const float*)eshv + (size_t)e*4);
            sh0 = r.x; sh1x = r.y; sh1y = r.z; sh1z = r.w;
            const float4* qq = (const float4*)((const float*)nfv + (size_t)src*40);
            #pragma unroll
            for (int i=0;i<10;i++){
                float4 t = qq[i];
                f[i*4+0]=t.x; f[i*4+1]=t.y; f[i*4+2]=t.z; f[i*4+3]=t.w;
            }
            const float4* qb = (const float4*)((const float*)ebv + (size_t)e*8);
            float4 t0 = qb[0], t1 = qb[1];
            bas[0]=t0.x; bas[1]=t0.y; bas[2]=t0.z; bas[3]=t0.w;
            bas[4]=t1.x; bas[5]=t1.y; bas[6]=t1.z; bas[7]=t1.w;
        }
    }

    // ---- MLP1 ----
    const float* W1T = ws + OFF_W1T;
    const float* b1f = ws + OFF_B1;
    float h1[64];
    #pragma unroll
    for (int j=0;j<64;j++){
        const float* w = W1T + j*8;
        float t0 = b1f[j] + bas[0]*w[0] + bas[4]*w[4];
        float t1 = bas[1]*w[1] + bas[5]*w[5];
        float t2 = bas[2]*w[2] + bas[6]*w[6];
        float t3 = bas[3]*w[3] + bas[7]*w[7];
        h1[j] = siluf_((t0+t1)+(t2+t3));
    }

    // ---- MLP2 -> bf16 h2 rows in LDS ----
    const float* W2T = ws + OFF_W2T;
    const float* b2f = ws + OFF_B2;
    #pragma unroll 1
    for (int j=0;j<64;j++){
        const float* w = W2T + j*64;
        float t0=b2f[j], t1=0.f, t2=0.f, t3=0.f;
        #pragma unroll
        for (int k=0;k<64;k+=4){
            t0 += h1[k]*w[k];     t1 += h1[k+1]*w[k+1];
            t2 += h1[k+2]*w[k+2]; t3 += h1[k+3]*w[k+3];
        }
        h2hi[lane][j] = f2bf(siluf_((t0+t1)+(t2+t3)));
    }
    __syncthreads();

    // ---- A fragments (consume all of h2 into registers) ----
    bf16x8 Afr[4][2];
    #pragma unroll
    for (int g=0;g<4;g++){
        Afr[g][0] = *(const bf16x8*)&h2hi[g*16+m][quad*8];
        Afr[g][1] = *(const bf16x8*)&h2hi[g*16+m][32 + quad*8];
    }
    __syncthreads();   // h2 region now dead -> tpb may overlay

    // ---- per-thread contraction coefficients ----
    float cssx[16], vxsh0[24], dvv[8];
    #pragma unroll
    for (int u=0;u<16;u++) cssx[u] = f[u]*sh0;
    #pragma unroll
    for (int j=0;j<24;j++) vxsh0[j] = f[16+j]*sh0;
    #pragma unroll
    for (int u=0;u<8;u++)
        dvv[u] = (f[16+u*3]*sh1x + f[17+u*3]*sh1y + f[18+u*3]*sh1z)*INV_SQRT3_C;

    float outs[24], tsv[8], av0[8], av1[8], av2[8];
    #pragma unroll
    for (int t=0;t<24;t++) outs[t]=0.f;
    #pragma unroll
    for (int t=0;t<8;t++){ tsv[t]=0.f; av0[t]=0.f; av1[t]=0.f; av2[t]=0.f; }

    const short* BH = (const short*)(ws + OFF_W3T);
    const short* BL = BH + 49152;
    const float* b3f = ws + OFF_B3;

    auto loadB = [&](bf16x8* dst2, int cc2){
        #pragma unroll
        for (int ntl=0; ntl<3; ntl++){
            const int nt = cc2*3 + ntl;
            dst2[ntl*4+0] = *(const bf16x8*)(BH + ((nt*2+0)*64 + lane)*8);
            dst2[ntl*4+1] = *(const bf16x8*)(BL + ((nt*2+0)*64 + lane)*8);
            dst2[ntl*4+2] = *(const bf16x8*)(BH + ((nt*2+1)*64 + lane)*8);
            dst2[ntl*4+3] = *(const bf16x8*)(BL + ((nt*2+1)*64 + lane)*8);
        }
    };

    bf16x8 Bcur[12], Bnxt[12];
    loadB(Bcur, 0);

    #pragma unroll 1
    for (int cc=0; cc<16; cc++){
        if (cc < 15) loadB(Bnxt, cc+1);

        #pragma unroll
        for (int ntl=0; ntl<3; ntl++){
            #pragma unroll
            for (int g=0; g<4; g++){
                f32x4 acc = {0.f,0.f,0.f,0.f};
                acc = __builtin_amdgcn_mfma_f32_16x16x32_bf16(Afr[g][0], Bcur[ntl*4+0], acc, 0,0,0);
                acc = __builtin_amdgcn_mfma_f32_16x16x32_bf16(Afr[g][0], Bcur[ntl*4+1], acc, 0,0,0);
                acc = __builtin_amdgcn_mfma_f32_16x16x32_bf16(Afr[g][1], Bcur[ntl*4+2], acc, 0,0,0);
                acc = __builtin_amdgcn_mfma_f32_16x16x32_bf16(Afr[g][1], Bcur[ntl*4+3], acc, 0,0,0);
                #pragma unroll
                for (int r=0;r<4;r++) tpb[g*16+quad*4+r][ntl*16+m] = acc[r];
            }
        }
        __syncthreads();

        float vals[48];
        #pragma unroll
        for (int c=0;c<48;c++) vals[c] = tpb[lane][c] + b3f[cc*48+c];

        if (cc < 8){
            float cA = sel8(cssx[0],cssx[2],cssx[4],cssx[6],cssx[8],cssx[10],cssx[12],cssx[14], cc);
            float cB = sel8(cssx[1],cssx[3],cssx[5],cssx[7],cssx[9],cssx[11],cssx[13],cssx[15], cc);
            #pragma unroll
            for (int c=0;c<24;c++) outs[c] += cA*vals[c];
            #pragma unroll
            for (int c=0;c<24;c++) outs[c] += cB*vals[24+c];
        } else if (cc < 12){
            int q = cc-8;
            float cA = sel4(dvv[0],dvv[2],dvv[4],dvv[6], q);
            float cB = sel4(dvv[1],dvv[3],dvv[5],dvv[7], q);
            #pragma unroll
            for (int c=0;c<24;c++) outs[c] += cA*vals[c];
            #pragma unroll
            for (int c=0;c<24;c++) outs[c] += cB*vals[24+c];
        } else if (cc == 12){
            #pragma unroll
            for (int c=0;c<48;c++) tsv[c&7] += f[c>>3]*vals[c];
        } else if (cc == 13){
            #pragma unroll
            for (int c=0;c<48;c++) tsv[c&7] += f[6+(c>>3)]*vals[c];
        } else if (cc == 14){
            #pragma unroll
            for (int c=0;c<32;c++) tsv[c&7] += f[12+(c>>3)]*vals[c];
            #pragma unroll
            for (int c=32;c<48;c++){
                const int u=(c-32)>>3, w=(c-32)&7;
                av0[w] += vxsh0[u*3+0]*vals[c];
                av1[w] += vxsh0[u*3+1]*vals[c];
                av2[w] += vxsh0[u*3+2]*vals[c];
            }
        } else {
            #pragma unroll
            for (int c=0;c<48;c++){
                const int u=2+(c>>3), w=c&7;
                av0[w] += vxsh0[u*3+0]*vals[c];
                av1[w] += vxsh0[u*3+1]*vals[c];
                av2[w] += vxsh0[u*3+2]*vals[c];
            }
        }
        __syncthreads();

        #pragma unroll
        for (int i=0;i<12;i++) Bcur[i] = Bnxt[i];
    }

    if (act){
        if (SORTED){
            // scattered full-line stores to msg[slot][48]
            float v48[48];
            #pragma unroll
            for (int w=0;w<24;w++) v48[w] = outs[w]*ALPHA_C;
            #pragma unroll
            for (int w=0;w<8;w++){
                v48[24+w*3+0] = (tsv[w]*sh1x + av0[w])*ALPHA_C;
                v48[24+w*3+1] = (tsv[w]*sh1y + av1[w])*ALPHA_C;
                v48[24+w*3+2] = (tsv[w]*sh1z + av2[w])*ALPHA_C;
            }
            float4* mp = (float4*)(outbuf + (size_t)slot*48);
            #pragma unroll
            for (int q=0;q<12;q++) mp[q] = make_float4(v48[q*4],v48[q*4+1],v48[q*4+2],v48[q*4+3]);
        } else {
            const int dst = eidx[N_EDGES_C + e];
            float* dp = outbuf + (size_t)dst*48;
            #pragma unroll
            for (int w=0;w<24;w++) atomicAdd(dp+w, outs[w]*ALPHA_C);
            #pragma unroll
            for (int w=0;w<8;w++){
                atomicAdd(dp+24+w*3+0, (tsv[w]*sh1x + av0[w])*ALPHA_C);
                atomicAdd(dp+24+w*3+1, (tsv[w]*sh1y + av1[w])*ALPHA_C);
                atomicAdd(dp+24+w*3+2, (tsv[w]*sh1z + av2[w])*ALPHA_C);
            }
        }
    }
}

// ---------------- node kernel (templated source of agg) ----------------
template<bool SORTED>
__global__ __launch_bounds__(256) void node_kernel_t(
    const float* __restrict__ ws,
    const float* __restrict__ msg,     // SORTED only
    const int* __restrict__ start,     // SORTED only
    float* __restrict__ svb,           // agg region: read (atomic path) / write svb
    float* __restrict__ stats)
{
    const float* si0T = ws + OFF_SI0;
    const float* si1T = ws + OFF_SI1;
    const int n = blockIdx.x*256 + threadIdx.x;
    const bool act = n < N_NODES_C;

    float a[48];
    #pragma unroll
    for (int j=0;j<48;j++) a[j]=0.f;
    if (act){
        if (SORTED){
            int s = start[n], en = start[n+1];
            #pragma unroll 1
            for (int r=s; r<en; ++r){
                const float4* mp = (const float4*)(msg + (size_t)r*48);
                #pragma unroll
                for (int q=0;q<12;q++){
                    float4 t = mp[q];
                    a[q*4]+=t.x; a[q*4+1]+=t.y; a[q*4+2]+=t.z; a[q*4+3]+=t.w;
                }
            }
        } else {
            const float4* p = (const float4*)(svb + (size_t)n*48);
            #pragma unroll
            for (int q=0;q<12;q++){ float4 r=p[q]; a[q*4]=r.x; a[q*4+1]=r.y; a[q*4+2]=r.z; a[q*4+3]=r.w; }
        }
    }
    float spre[16];
    #pragma unroll
    for (int u=0;u<16;u++) spre[u]=siluf_(a[u]);
    float v[24];
    #pragma unroll
    for (int u=0;u<8;u++){
        float g = sigmoidf_(a[16+u]);
        v[u*3+0]=a[24+u*3+0]*g; v[u*3+1]=a[24+u*3+1]*g; v[u*3+2]=a[24+u*3+2]*g;
    }
    float so[16];
    #pragma unroll
    for (int w=0;w<16;w++){
        const float* c = si0T + w*16;
        float t0=0.f,t1=0.f,t2=0.f,t3=0.f;
        #pragma unroll
        for (int u=0;u<16;u+=4){ t0+=spre[u]*c[u]; t1+=spre[u+1]*c[u+1]; t2+=spre[u+2]*c[u+2]; t3+=spre[u+3]*c[u+3]; }
        so[w]=(t0+t1)+(t2+t3);
    }
    float vo[24];
    #pragma unroll
    for (int w=0;w<8;w++){
        const float* c = si1T + w*8;
        float a0=0.f,a1=0.f,a2=0.f;
        #pragma unroll
        for (int u=0;u<8;u++){ a0+=v[u*3]*c[u]; a1+=v[u*3+1]*c[u]; a2+=v[u*3+2]*c[u]; }
        vo[w*3]=a0; vo[w*3+1]=a1; vo[w*3+2]=a2;
    }
    if (act){
        float4* op = (float4*)(svb + (size_t)n*48);
        op[0]=make_float4(so[0],so[1],so[2],so[3]);
        op[1]=make_float4(so[4],so[5],so[6],so[7]);
        op[2]=make_float4(so[8],so[9],so[10],so[11]);
        op[3]=make_float4(so[12],so[13],so[14],so[15]);
        #pragma unroll
        for (int q=0;q<6;q++) op[4+q]=make_float4(vo[q*4],vo[q*4+1],vo[q*4+2],vo[q*4+3]);
    }
    float r[40];
    #pragma unroll
    for (int w=0;w<16;w++){ r[w]=so[w]; r[16+w]=so[w]*so[w]; }
    #pragma unroll
    for (int w=0;w<8;w++) r[32+w]=(vo[w*3]*vo[w*3]+vo[w*3+1]*vo[w*3+1]+vo[w*3+2]*vo[w*3+2])*(1.0f/3.0f);
    #pragma unroll
    for (int j=0;j<40;j++){
        float x = r[j];
        for (int off=32; off; off>>=1) x += __shfl_down(x, off);
        r[j]=x;
    }
    if ((threadIdx.x & 63)==0){
        #pragma unroll
        for (int j=0;j<40;j++) atomicAdd(stats+j, r[j]);
    }
}

// ---------------- finalize ----------------
__global__ __launch_bounds__(256) void final_kernel(
    const float* __restrict__ ws, const float* __restrict__ svb,
    const void* __restrict__ nfv,
    const void* __restrict__ bnws, const void* __restrict__ bnbs,
    const void* __restrict__ bnwv,
    void* __restrict__ outv)
{
    const float* stats = ws + OFF_STATS;
    const bool fm = ((const u32*)(ws + OFF_FLAG))[0] != 0u;
    const int n = blockIdx.x*256 + threadIdx.x;
    if (n >= N_NODES_C) return;
    const float invN = 1.0f/(float)N_NODES_C;
    const float* s = svb + (size_t)n*48;
    float nfr[40];
    if (!fm){
        const uint4* q = (const uint4*)((const __hip_bfloat16*)nfv + (size_t)n*40);
        #pragma unroll
        for (int i=0;i<5;i++){
            uint4 r = q[i];
            nfr[i*8+0]=bflo(r.x); nfr[i*8+1]=bfhi(r.x);
            nfr[i*8+2]=bflo(r.y); nfr[i*8+3]=bfhi(r.y);
            nfr[i*8+4]=bflo(r.z); nfr[i*8+5]=bfhi(r.z);
            nfr[i*8+6]=bflo(r.w); nfr[i*8+7]=bfhi(r.w);
        }
    } else {
        const float4* q = (const float4*)((const float*)nfv + (size_t)n*40);
        #pragma unroll
        for (int i=0;i<10;i++){
            float4 t = q[i];
            nfr[i*4+0]=t.x; nfr[i*4+1]=t.y; nfr[i*4+2]=t.z; nfr[i*4+3]=t.w;
        }
    }
    float vals[40];
    #pragma unroll
    for (int w=0;w<16;w++){
        float mean = stats[w]*invN;
        float var  = fmaxf(stats[16+w]*invN - mean*mean, 0.0f);
        float is   = rsqrtf(var + BN_EPS_C) * rdv(bnws, w, fm);
        vals[w] = (s[w]-mean)*is + rdv(bnbs, w, fm) + nfr[w];
    }
    #pragma unroll
    for (int w=0;w<8;w++){
        float iv = rsqrtf(fmaxf(stats[32+w]*invN, 0.0f) + BN_EPS_C) * rdv(bnwv, w, fm);
        vals[16+w*3+0] = s[16+w*3+0]*iv + nfr[16+w*3+0];
        vals[16+w*3+1] = s[16+w*3+1]*iv + nfr[16+w*3+1];
        vals[16+w*3+2] = s[16+w*3+2]*iv + nfr[16+w*3+2];
    }
    if (!fm){
        u32 packed[20];
        #pragma unroll
        for (int q=0;q<20;q++) packed[q] = (u32)f2bf(vals[2*q]) | ((u32)f2bf(vals[2*q+1])<<16);
        uint4* op = (uint4*)((u16*)outv + (size_t)n*40);
        #pragma unroll
        for (int q=0;q<5;q++) op[q] = make_uint4(packed[q*4],packed[q*4+1],packed[q*4+2],packed[q*4+3]);
    } else {
        float4* op = (float4*)((float*)outv + (size_t)n*40);
        #pragma unroll
        for (int q=0;q<10;q++) op[q] = make_float4(vals[q*4],vals[q*4+1],vals[q*4+2],vals[q*4+3]);
    }
}

extern "C" void kernel_launch(void* const* d_in, const int* in_sizes, int n_in,
                              void* d_out, int out_size, void* d_ws, size_t ws_size,
                              hipStream_t stream)
{
    const void* nf     = d_in[0];
    const void* esh    = d_in[1];
    const void* ebasis = d_in[2];
    const int*  eidx   = (const int*)d_in[3];
    const void* W1 = d_in[4];
    const void* b1 = d_in[5];
    const void* W2 = d_in[6];
    const void* b2 = d_in[7];
    const void* W3 = d_in[8];
    const void* b3 = d_in[9];
    const void* si0 = d_in[10];
    const void* si1 = d_in[11];
    const void* bnws = d_in[12];
    const void* bnbs = d_in[13];
    const void* bnwv = d_in[14];

    float* ws    = (float*)d_ws;
    float* stats = ws + OFF_STATS;
    float* agg   = ws + OFF_AGG;

    if (ws_size < REQ_WS_BYTES){
        int nw = out_size/2;
        fill_kernel<<<(nw+255)/256, 256, 0, stream>>>((u32*)d_out, nw, 0x447A447Au);
        return;
    }

    const int* dst = eidx + N_EDGES_C;
    const int EB = (N_EDGES_C+255)/256;

    hipMemsetAsync(stats, 0, 48*sizeof(float), stream);
    detect_kernel<<<1, 64, 0, stream>>>((const u32*)nf, (u32*)(ws + OFF_FLAG));
    prep_kernel<<<215, 256, 0, stream>>>(W1,b1,W2,b2,W3,b3,si0,si1, ws);

    if (ws_size >= REQ2_WS_BYTES){
        // ---- sorted (atomic-free aggregation) path ----
        int*   deg    = (int*)(ws + OFF_DEG);
        int*   startp = (int*)(ws + OFF_START);
        int*   cursor = (int*)(ws + OFF_CURSOR);
        int*   pos    = (int*)(ws + OFF_POS);
        float* msg    = ws + OFF_MSG;

        hipMemsetAsync(deg, 0, N_NODES_C*sizeof(int), stream);
        count_kernel<<<EB, 256, 0, stream>>>(dst, deg);
        scan_kernel<<<1, 1024, 0, stream>>>(deg, startp, cursor);
        scatter_kernel<<<EB, 256, 0, stream>>>(dst, cursor, pos);
        edge_kernel_t<true><<<(N_EDGES_C+63)/64, 64, 0, stream>>>(nf, esh, ebasis, eidx, ws, pos, msg);
        node_kernel_t<true><<<(N_NODES_C+255)/256, 256, 0, stream>>>(ws, msg, startp, agg, stats);
    } else {
        // ---- fallback: round-9 verified atomic path ----
        hipMemsetAsync(agg, 0, (size_t)2400000*sizeof(float), stream);
        edge_kernel_t<false><<<(N_EDGES_C+63)/64, 64, 0, stream>>>(nf, esh, ebasis, eidx, ws, nullptr, agg);
        node_kernel_t<false><<<(N_NODES_C+255)/256, 256, 0, stream>>>(ws, nullptr, nullptr, agg, stats);
    }
    final_kernel<<<(N_NODES_C+255)/256, 256, 0, stream>>>(ws, agg, nf, bnws, bnbs, bnwv, d_out);
}